// Round 5
// baseline (596.782 us; speedup 1.0000x reference)
//
#include <hip/hip_runtime.h>
#include <hip/hip_bf16.h>

#define Hh 128
#define Ww 160
#define Cc 32
#define Dd 48
#define Bb 2
#define Vv 3
#define HW (Hh*Ww)
#define CP2 20   // padded stride for 16-channel half-tile (16 + 4 pad floats)

// ---------------- K0: proj = src_proj @ inv(ref_proj), extract rot/trans ----
__global__ void k_proj(const float* __restrict__ pm, float* __restrict__ P) {
    int t = threadIdx.x;
    if (t >= Bb * (Vv - 1)) return;
    int b = t >> 1;
    int v = (t & 1) + 1;
    const float* ref = pm + (b * Vv + 0) * 16;
    const float* src = pm + (b * Vv + v) * 16;
    float A[4][8];
    for (int i = 0; i < 4; ++i)
        for (int j = 0; j < 4; ++j) {
            A[i][j] = ref[i * 4 + j];
            A[i][4 + j] = (i == j) ? 1.0f : 0.0f;
        }
    for (int col = 0; col < 4; ++col) {
        int piv = col;
        for (int r = col + 1; r < 4; ++r)
            if (fabsf(A[r][col]) > fabsf(A[piv][col])) piv = r;
        if (piv != col)
            for (int j = 0; j < 8; ++j) { float tmp = A[col][j]; A[col][j] = A[piv][j]; A[piv][j] = tmp; }
        float inv = 1.0f / A[col][col];
        for (int j = 0; j < 8; ++j) A[col][j] *= inv;
        for (int r = 0; r < 4; ++r) {
            if (r == col) continue;
            float f = A[r][col];
            for (int j = 0; j < 8; ++j) A[r][j] -= f * A[col][j];
        }
    }
    float Pm[3][4];
    for (int i = 0; i < 3; ++i)
        for (int j = 0; j < 4; ++j) {
            float s = 0.f;
            for (int k = 0; k < 4; ++k) s += src[i * 4 + k] * A[k][4 + j];
            Pm[i][j] = s;
        }
    float* o = P + t * 12;
    o[0] = Pm[0][0]; o[1] = Pm[0][1]; o[2] = Pm[0][2];
    o[3] = Pm[1][0]; o[4] = Pm[1][1]; o[5] = Pm[1][2];
    o[6] = Pm[2][0]; o[7] = Pm[2][1]; o[8] = Pm[2][2];
    o[9] = Pm[0][3]; o[10] = Pm[1][3]; o[11] = Pm[2][3];
}

// ---------------- K1: transpose (v,b,c,h,w) -> (v,b,h,w,c) ------------------
__global__ void k_transpose(const float* __restrict__ f, float* __restrict__ featT) {
    __shared__ float t[Cc][Ww + 1];
    int slice = blockIdx.x;          // vb*H + y
    int vb = slice / Hh, y = slice % Hh;
    const float* src = f + (size_t)vb * Cc * HW + (size_t)y * Ww;
    float* dst = featT + ((size_t)vb * Hh + y) * Ww * Cc;
    for (int i = threadIdx.x; i < Cc * Ww; i += 256) {
        int c = i / Ww, x = i - c * Ww;
        t[c][x] = src[(size_t)c * HW + x];
    }
    __syncthreads();
    for (int i = threadIdx.x; i < Cc * Ww; i += 256) {
        int x = i >> 5, c = i & 31;
        dst[i] = t[c][x];
    }
}

// ---------------- K2: variance tile + channel-contracted 3x3 conv -> S ------
// Two 16-channel halves through a 26 KB LDS tile.
// Register-pressure history: full c4-unroll schedules ~144 regs of in-flight
// loads -> true pressure ~170 -> (256,6)/(256,4) spilled GBs of scratch
// (R2/R3); (256,3) hid it in AGPRs but capped occupancy at 12 waves/CU (R4).
// Fix: unroll 1 on the load loops (one 9-load batch in flight ~= 70 regs
// total) + launch_bounds(256,5) -> 20 waves/CU with zero spill.
__global__ __launch_bounds__(256, 5)
void k_main(const float* __restrict__ featT, const float* __restrict__ P,
            const float* __restrict__ dvals, const float* __restrict__ wt,
            float* __restrict__ S) {
    __shared__ float vsh[324 * CP2];
    __shared__ float rt[24];
    const int tid = threadIdx.x;
    const int b = blockIdx.z, d = blockIdx.y;
    const int tileY = blockIdx.x / 10, tileX = blockIdx.x - (blockIdx.x / 10) * 10;

    if (tid < 24) rt[tid] = P[b * 24 + tid];
    const float depth = dvals[b * Dd + d];
    const int ty = tid >> 4, tx = tid & 15;
    float acc0 = 0.f, acc1 = 0.f, acc2 = 0.f;
    __syncthreads();

#pragma unroll 1
    for (int half = 0; half < 2; ++half) {
        const int coff = half * 16;   // channel offset (floats) into featT pixel
        const float* b1 = featT + (size_t)(1 * Bb + b) * HW * Cc + coff;
        const float* b2 = featT + (size_t)(2 * Bb + b) * HW * Cc + coff;

        // ---- phase 1: fill 18x18 halo variance tile for 16 channels ----
#pragma unroll 1
        for (int p = tid; p < 324; p += 256) {
            int pyt = p / 18, pxt = p - pyt * 18;
            int gy = tileY * 16 + pyt - 1, gx = tileX * 16 + pxt - 1;
            float* dst = &vsh[p * CP2];
            if ((unsigned)gy >= (unsigned)Hh || (unsigned)gx >= (unsigned)Ww) {
                float4 z4 = make_float4(0.f, 0.f, 0.f, 0.f);
#pragma unroll
                for (int c4 = 0; c4 < 4; ++c4) *(float4*)&dst[c4 * 4] = z4;
                continue;
            }
            int   off[2][4];
            float wgt[2][4];
#pragma unroll
            for (int vi = 0; vi < 2; ++vi) {
                const float* M = &rt[vi * 12];
                float fgx = (float)gx, fgy = (float)gy;
                float rx = M[0] * fgx + M[1] * fgy + M[2];
                float ry = M[3] * fgx + M[4] * fgy + M[5];
                float rz = M[6] * fgx + M[7] * fgy + M[8];
                float X = rx * depth + M[9];
                float Y = ry * depth + M[10];
                float Z = rz * depth + M[11];
                float z = (fabsf(Z) < 1e-6f) ? 1e-6f : Z;
                float u = X / z, vv = Y / z;
                float x0f = floorf(u), y0f = floorf(vv);
                float fx = u - x0f, fy = vv - y0f;
                int x0 = (int)x0f, y0 = (int)y0f;
                int x1 = x0 + 1, y1 = y0 + 1;
                bool vx0 = (x0 >= 0) && (x0 <= Ww - 1);
                bool vx1 = (x1 >= 0) && (x1 <= Ww - 1);
                bool vy0 = (y0 >= 0) && (y0 <= Hh - 1);
                bool vy1 = (y1 >= 0) && (y1 <= Hh - 1);
                int xc0 = min(max(x0, 0), Ww - 1), xc1 = min(max(x1, 0), Ww - 1);
                int yc0 = min(max(y0, 0), Hh - 1), yc1 = min(max(y1, 0), Hh - 1);
                off[vi][0] = (yc0 * Ww + xc0) * Cc;
                off[vi][1] = (yc0 * Ww + xc1) * Cc;
                off[vi][2] = (yc1 * Ww + xc0) * Cc;
                off[vi][3] = (yc1 * Ww + xc1) * Cc;
                wgt[vi][0] = (vx0 && vy0) ? (1.f - fx) * (1.f - fy) : 0.f;
                wgt[vi][1] = (vx1 && vy0) ? fx * (1.f - fy) : 0.f;
                wgt[vi][2] = (vx0 && vy1) ? (1.f - fx) * fy : 0.f;
                wgt[vi][3] = (vx1 && vy1) ? fx * fy : 0.f;
            }
            const float* pref = featT + ((size_t)b * Hh + gy) * Ww * Cc + (size_t)gx * Cc + coff;
            const float i3 = 1.0f / 3.0f, i9 = 1.0f / 9.0f;
#pragma unroll 1
            for (int c4 = 0; c4 < 4; ++c4) {
                float4 r = *(const float4*)(pref + c4 * 4);
                float4 sum = r;
                float4 sq;
                sq.x = r.x * r.x; sq.y = r.y * r.y; sq.z = r.z * r.z; sq.w = r.w * r.w;
#pragma unroll
                for (int vi = 0; vi < 2; ++vi) {
                    const float* bs = (vi == 0) ? b1 : b2;
                    float4 c0 = *(const float4*)(bs + off[vi][0] + c4 * 4);
                    float4 c1 = *(const float4*)(bs + off[vi][1] + c4 * 4);
                    float4 c2 = *(const float4*)(bs + off[vi][2] + c4 * 4);
                    float4 c3 = *(const float4*)(bs + off[vi][3] + c4 * 4);
                    float w0 = wgt[vi][0], w1 = wgt[vi][1], w2 = wgt[vi][2], w3 = wgt[vi][3];
                    float4 s;
                    s.x = w0 * c0.x + w1 * c1.x + w2 * c2.x + w3 * c3.x;
                    s.y = w0 * c0.y + w1 * c1.y + w2 * c2.y + w3 * c3.y;
                    s.z = w0 * c0.z + w1 * c1.z + w2 * c2.z + w3 * c3.z;
                    s.w = w0 * c0.w + w1 * c1.w + w2 * c2.w + w3 * c3.w;
                    sum.x += s.x; sum.y += s.y; sum.z += s.z; sum.w += s.w;
                    sq.x += s.x * s.x; sq.y += s.y * s.y; sq.z += s.z * s.z; sq.w += s.w * s.w;
                }
                float4 var;
                var.x = sq.x * i3 - sum.x * sum.x * i9;
                var.y = sq.y * i3 - sum.y * sum.y * i9;
                var.z = sq.z * i3 - sum.z * sum.z * i9;
                var.w = sq.w * i3 - sum.w * sum.w * i9;
                *(float4*)&dst[c4 * 4] = var;
            }
        }
        __syncthreads();

        // ---- phase 2: 3x3 conv over 16 channels, 3 kd taps per thread ----
        // Accumulate straight off each LDS float4 tap (no vk staging array).
#pragma unroll 1
        for (int c4 = 0; c4 < 4; ++c4) {
            const float* w0 = wt + (coff + c4 * 4 + 0) * 27;   // wave-uniform -> s_load
            const float* w1 = wt + (coff + c4 * 4 + 1) * 27;
            const float* w2 = wt + (coff + c4 * 4 + 2) * 27;
            const float* w3 = wt + (coff + c4 * 4 + 3) * 27;
#pragma unroll
            for (int kh = 0; kh < 3; ++kh)
#pragma unroll
                for (int kw = 0; kw < 3; ++kw) {
                    int k9 = kh * 3 + kw;
                    float4 t4 = *(const float4*)&vsh[((ty + kh) * 18 + tx + kw) * CP2 + c4 * 4];
                    acc0 += t4.x * w0[k9]      + t4.y * w1[k9]      + t4.z * w2[k9]      + t4.w * w3[k9];
                    acc1 += t4.x * w0[9 + k9]  + t4.y * w1[9 + k9]  + t4.z * w2[9 + k9]  + t4.w * w3[9 + k9];
                    acc2 += t4.x * w0[18 + k9] + t4.y * w1[18 + k9] + t4.z * w2[18 + k9] + t4.w * w3[18 + k9];
                }
        }
        if (half == 0) __syncthreads();   // protect vsh before next half overwrites
    }

    int gy = tileY * 16 + ty, gx = tileX * 16 + tx;
    size_t pix = (size_t)gy * Ww + gx;
    size_t p0 = ((size_t)(b * 3 + 0) * Dd + d) * HW + pix;
    size_t p1 = ((size_t)(b * 3 + 1) * Dd + d) * HW + pix;
    size_t p2 = ((size_t)(b * 3 + 2) * Dd + d) * HW + pix;
    S[p0] = acc0; S[p1] = acc1; S[p2] = acc2;
}

// ---------------- K3: cost from S, softmax over D, depth + conf -------------
__global__ __launch_bounds__(256)
void k_post(const float* __restrict__ S, const float* __restrict__ dvals,
            float* __restrict__ out) {
    int gid = blockIdx.x * 256 + threadIdx.x;      // 0..B*HW-1
    int b = gid / HW;
    int pix = gid - b * HW;
    const float* S0 = S + ((size_t)(b * 3 + 0) * Dd) * HW + pix;
    const float* S1 = S + ((size_t)(b * 3 + 1) * Dd) * HW + pix;
    const float* S2 = S + ((size_t)(b * 3 + 2) * Dd) * HW + pix;
    float cost[Dd];
#pragma unroll
    for (int d = 0; d < Dd; ++d) {
        float cst = S1[(size_t)d * HW];
        if (d > 0)      cst += S0[(size_t)(d - 1) * HW];
        if (d < Dd - 1) cst += S2[(size_t)(d + 1) * HW];
        cost[d] = cst;
    }
    float m = cost[0];
#pragma unroll
    for (int d = 1; d < Dd; ++d) m = fmaxf(m, cost[d]);
    float sum = 0.f;
#pragma unroll
    for (int d = 0; d < Dd; ++d) { float e = expf(cost[d] - m); cost[d] = e; sum += e; }
    float inv = 1.0f / sum;
    float dep = 0.f, di = 0.f;
#pragma unroll
    for (int d = 0; d < Dd; ++d) {
        float pr = cost[d] * inv;
        dep += pr * dvals[b * Dd + d];
        di += pr * (float)d;
    }
    int didx = (int)di;
    didx = min(max(didx, 0), Dd - 1);
    float conf = 0.f;
#pragma unroll
    for (int d = 0; d < Dd; ++d)
        conf += ((d >= didx - 1) && (d <= didx + 2)) ? cost[d] : 0.f;
    conf *= inv;
    out[gid] = dep;
    out[Bb * HW + gid] = conf;
}

// ---------------- launch ----------------------------------------------------
extern "C" void kernel_launch(void* const* d_in, const int* in_sizes, int n_in,
                              void* d_out, int out_size, void* d_ws, size_t ws_size,
                              hipStream_t stream) {
    const float* features = (const float*)d_in[0];   // (V,B,C,H,W)
    const float* pm       = (const float*)d_in[1];   // (B,V,4,4)
    const float* dvals    = (const float*)d_in[2];   // (B,D)
    const float* reg_w    = (const float*)d_in[4];   // (1,C,3,3,3)
    float* outp = (float*)d_out;

    char* ws = (char*)d_ws;
    float* featT = (float*)ws;                                   // V*B*H*W*C floats
    size_t featT_bytes = (size_t)Vv * Bb * Hh * Ww * Cc * sizeof(float);
    float* P = (float*)(ws + featT_bytes);                       // 48 floats
    float* S = (float*)(ws + featT_bytes + 512);                 // B*3*D*H*W floats

    k_proj<<<1, 64, 0, stream>>>(pm, P);
    k_transpose<<<Vv * Bb * Hh, 256, 0, stream>>>(features, featT);
    k_main<<<dim3(80, Dd, Bb), 256, 0, stream>>>(featT, P, dvals, reg_w, S);
    k_post<<<(Bb * HW) / 256, 256, 0, stream>>>(S, dvals, outp);
}

// Round 6
// 222.456 us; speedup vs baseline: 2.6827x; 2.6827x over previous
//
#include <hip/hip_runtime.h>
#include <hip/hip_bf16.h>
#include <hip/hip_fp16.h>

#define Hh 128
#define Ww 160
#define Cc 32
#define Dd 48
#define Bb 2
#define Vv 3
#define HW (Hh*Ww)
#define CP2 20   // padded stride for 16-channel half-tile (16 + 4 pad floats)

// ---------------- K0: proj = src_proj @ inv(ref_proj), extract rot/trans ----
__global__ void k_proj(const float* __restrict__ pm, float* __restrict__ P) {
    int t = threadIdx.x;
    if (t >= Bb * (Vv - 1)) return;
    int b = t >> 1;
    int v = (t & 1) + 1;
    const float* ref = pm + (b * Vv + 0) * 16;
    const float* src = pm + (b * Vv + v) * 16;
    float A[4][8];
    for (int i = 0; i < 4; ++i)
        for (int j = 0; j < 4; ++j) {
            A[i][j] = ref[i * 4 + j];
            A[i][4 + j] = (i == j) ? 1.0f : 0.0f;
        }
    for (int col = 0; col < 4; ++col) {
        int piv = col;
        for (int r = col + 1; r < 4; ++r)
            if (fabsf(A[r][col]) > fabsf(A[piv][col])) piv = r;
        if (piv != col)
            for (int j = 0; j < 8; ++j) { float tmp = A[col][j]; A[col][j] = A[piv][j]; A[piv][j] = tmp; }
        float inv = 1.0f / A[col][col];
        for (int j = 0; j < 8; ++j) A[col][j] *= inv;
        for (int r = 0; r < 4; ++r) {
            if (r == col) continue;
            float f = A[r][col];
            for (int j = 0; j < 8; ++j) A[r][j] -= f * A[col][j];
        }
    }
    float Pm[3][4];
    for (int i = 0; i < 3; ++i)
        for (int j = 0; j < 4; ++j) {
            float s = 0.f;
            for (int k = 0; k < 4; ++k) s += src[i * 4 + k] * A[k][4 + j];
            Pm[i][j] = s;
        }
    float* o = P + t * 12;
    o[0] = Pm[0][0]; o[1] = Pm[0][1]; o[2] = Pm[0][2];
    o[3] = Pm[1][0]; o[4] = Pm[1][1]; o[5] = Pm[1][2];
    o[6] = Pm[2][0]; o[7] = Pm[2][1]; o[8] = Pm[2][2];
    o[9] = Pm[0][3]; o[10] = Pm[1][3]; o[11] = Pm[2][3];
}

// ---------------- K1: transpose (v,b,c,h,w) -> (v,b,h,w,c) ------------------
__global__ void k_transpose(const float* __restrict__ f, float* __restrict__ featT) {
    __shared__ float t[Cc][Ww + 1];
    int slice = blockIdx.x;          // vb*H + y
    int vb = slice / Hh, y = slice % Hh;
    const float* src = f + (size_t)vb * Cc * HW + (size_t)y * Ww;
    float* dst = featT + ((size_t)vb * Hh + y) * Ww * Cc;
    for (int i = threadIdx.x; i < Cc * Ww; i += 256) {
        int c = i / Ww, x = i - c * Ww;
        t[c][x] = src[(size_t)c * HW + x];
    }
    __syncthreads();
    for (int i = threadIdx.x; i < Cc * Ww; i += 256) {
        int x = i >> 5, c = i & 31;
        dst[i] = t[c][x];
    }
}

// ---------------- K2: variance tile + channel-contracted 3x3 conv -> S ------
// Register-pressure history: keeping per-slot corner offsets/weights in
// registers while gathers are in flight forces ~160 true pressure; every
// launch_bounds >=4 spilled (R2/R3/R5: 0.5-3.5 GB scratch HBM traffic),
// (256,3) fit but capped 12 waves/CU (R1/R4, ~410-430 us, latency-bound).
// R6 fix: stage coords ONCE into LDS (cbuf: 8 dwords/slot = ushort pixel
// idx x8 + fp16 wgt x8), then gather items (slot,c4-quad) carry no state
// across iterations -> pressure ~80, launch_bounds(256,4), 36 KB LDS,
// 4 blocks/CU = 16 waves/CU.
__global__ __launch_bounds__(256, 4)
void k_main(const float* __restrict__ featT, const float* __restrict__ P,
            const float* __restrict__ dvals, const float* __restrict__ wt,
            float* __restrict__ S) {
    __shared__ float vsh[324 * CP2];          // 25.9 KB variance tile (16 ch)
    __shared__ unsigned int cbuf[324 * 8];    // 10.4 KB coord cache
    __shared__ float rt[24];
    const int tid = threadIdx.x;
    const int b = blockIdx.z, d = blockIdx.y;
    const int tileY = blockIdx.x / 10, tileX = blockIdx.x - (blockIdx.x / 10) * 10;

    if (tid < 24) rt[tid] = P[b * 24 + tid];
    const float depth = dvals[b * Dd + d];
    const int ty = tid >> 4, tx = tid & 15;
    float acc0 = 0.f, acc1 = 0.f, acc2 = 0.f;
    __syncthreads();

    // ---- stage A: coords for all 324 slots, once per block ----
#pragma unroll 1
    for (int p = tid; p < 324; p += 256) {
        int pyt = p / 18, pxt = p - pyt * 18;
        int gy = tileY * 16 + pyt - 1, gx = tileX * 16 + pxt - 1;
        if ((unsigned)gy >= (unsigned)Hh || (unsigned)gx >= (unsigned)Ww) continue;
        unsigned int* cb = &cbuf[p * 8];
#pragma unroll
        for (int vi = 0; vi < 2; ++vi) {
            const float* M = &rt[vi * 12];
            float fgx = (float)gx, fgy = (float)gy;
            float rx = M[0] * fgx + M[1] * fgy + M[2];
            float ry = M[3] * fgx + M[4] * fgy + M[5];
            float rz = M[6] * fgx + M[7] * fgy + M[8];
            float X = rx * depth + M[9];
            float Y = ry * depth + M[10];
            float Z = rz * depth + M[11];
            float z = (fabsf(Z) < 1e-6f) ? 1e-6f : Z;
            float u = X / z, vv = Y / z;
            float x0f = floorf(u), y0f = floorf(vv);
            float fx = u - x0f, fy = vv - y0f;
            int x0 = (int)x0f, y0 = (int)y0f;
            int x1 = x0 + 1, y1 = y0 + 1;
            bool vx0 = (x0 >= 0) && (x0 <= Ww - 1);
            bool vx1 = (x1 >= 0) && (x1 <= Ww - 1);
            bool vy0 = (y0 >= 0) && (y0 <= Hh - 1);
            bool vy1 = (y1 >= 0) && (y1 <= Hh - 1);
            int xc0 = min(max(x0, 0), Ww - 1), xc1 = min(max(x1, 0), Ww - 1);
            int yc0 = min(max(y0, 0), Hh - 1), yc1 = min(max(y1, 0), Hh - 1);
            unsigned int p00 = (unsigned)(yc0 * Ww + xc0);
            unsigned int p01 = (unsigned)(yc0 * Ww + xc1);
            unsigned int p10 = (unsigned)(yc1 * Ww + xc0);
            unsigned int p11 = (unsigned)(yc1 * Ww + xc1);
            float w0 = (vx0 && vy0) ? (1.f - fx) * (1.f - fy) : 0.f;
            float w1 = (vx1 && vy0) ? fx * (1.f - fy) : 0.f;
            float w2 = (vx0 && vy1) ? (1.f - fx) * fy : 0.f;
            float w3 = (vx1 && vy1) ? fx * fy : 0.f;
            cb[vi * 2 + 0] = p00 | (p01 << 16);
            cb[vi * 2 + 1] = p10 | (p11 << 16);
            __half2 ha = __floats2half2_rn(w0, w1);
            __half2 hb = __floats2half2_rn(w2, w3);
            cb[4 + vi * 2 + 0] = *(unsigned int*)&ha;
            cb[4 + vi * 2 + 1] = *(unsigned int*)&hb;
        }
    }
    __syncthreads();

#pragma unroll 1
    for (int half = 0; half < 2; ++half) {
        const int coff = half * 16;   // channel offset (floats) into featT pixel
        const float* b1 = featT + (size_t)(1 * Bb + b) * HW * Cc + coff;
        const float* b2 = featT + (size_t)(2 * Bb + b) * HW * Cc + coff;
        const float* br = featT + (size_t)b * HW * Cc + coff;

        // ---- stage B: gather items (slot, c4-quad): 1296 items ----
#pragma unroll 1
        for (int i = tid; i < 1296; i += 256) {
            int p = i >> 2, c4 = i & 3;
            int pyt = p / 18, pxt = p - pyt * 18;
            int gy = tileY * 16 + pyt - 1, gx = tileX * 16 + pxt - 1;
            float* dst = &vsh[p * CP2 + c4 * 4];
            if ((unsigned)gy >= (unsigned)Hh || (unsigned)gx >= (unsigned)Ww) {
                *(float4*)dst = make_float4(0.f, 0.f, 0.f, 0.f);
                continue;
            }
            uint4 oo = *(const uint4*)&cbuf[p * 8];
            uint4 wwp = *(const uint4*)&cbuf[p * 8 + 4];
            int o00 = (int)(oo.x & 0xffffu) * Cc + c4 * 4;
            int o01 = (int)(oo.x >> 16)     * Cc + c4 * 4;
            int o10 = (int)(oo.y & 0xffffu) * Cc + c4 * 4;
            int o11 = (int)(oo.y >> 16)     * Cc + c4 * 4;
            int o20 = (int)(oo.z & 0xffffu) * Cc + c4 * 4;
            int o21 = (int)(oo.z >> 16)     * Cc + c4 * 4;
            int o30 = (int)(oo.w & 0xffffu) * Cc + c4 * 4;
            int o31 = (int)(oo.w >> 16)     * Cc + c4 * 4;
            float2 wa = __half22float2(*(__half2*)&wwp.x);  // v0: w0,w1
            float2 wb = __half22float2(*(__half2*)&wwp.y);  // v0: w2,w3
            float2 wc = __half22float2(*(__half2*)&wwp.z);  // v1: w0,w1
            float2 wd = __half22float2(*(__half2*)&wwp.w);  // v1: w2,w3
            float4 r  = *(const float4*)(br + (size_t)(gy * Ww + gx) * Cc + c4 * 4);
            float4 c0 = *(const float4*)(b1 + o00);
            float4 c1 = *(const float4*)(b1 + o01);
            float4 c2 = *(const float4*)(b1 + o10);
            float4 c3 = *(const float4*)(b1 + o11);
            float4 e0 = *(const float4*)(b2 + o20);
            float4 e1 = *(const float4*)(b2 + o21);
            float4 e2 = *(const float4*)(b2 + o30);
            float4 e3 = *(const float4*)(b2 + o31);
            float4 s1, s2, sum, sq, var;
            s1.x = wa.x * c0.x + wa.y * c1.x + wb.x * c2.x + wb.y * c3.x;
            s1.y = wa.x * c0.y + wa.y * c1.y + wb.x * c2.y + wb.y * c3.y;
            s1.z = wa.x * c0.z + wa.y * c1.z + wb.x * c2.z + wb.y * c3.z;
            s1.w = wa.x * c0.w + wa.y * c1.w + wb.x * c2.w + wb.y * c3.w;
            s2.x = wc.x * e0.x + wc.y * e1.x + wd.x * e2.x + wd.y * e3.x;
            s2.y = wc.x * e0.y + wc.y * e1.y + wd.x * e2.y + wd.y * e3.y;
            s2.z = wc.x * e0.z + wc.y * e1.z + wd.x * e2.z + wd.y * e3.z;
            s2.w = wc.x * e0.w + wc.y * e1.w + wd.x * e2.w + wd.y * e3.w;
            const float i3 = 1.0f / 3.0f, i9 = 1.0f / 9.0f;
            sum.x = r.x + s1.x + s2.x; sum.y = r.y + s1.y + s2.y;
            sum.z = r.z + s1.z + s2.z; sum.w = r.w + s1.w + s2.w;
            sq.x = r.x * r.x + s1.x * s1.x + s2.x * s2.x;
            sq.y = r.y * r.y + s1.y * s1.y + s2.y * s2.y;
            sq.z = r.z * r.z + s1.z * s1.z + s2.z * s2.z;
            sq.w = r.w * r.w + s1.w * s1.w + s2.w * s2.w;
            var.x = sq.x * i3 - sum.x * sum.x * i9;
            var.y = sq.y * i3 - sum.y * sum.y * i9;
            var.z = sq.z * i3 - sum.z * sum.z * i9;
            var.w = sq.w * i3 - sum.w * sum.w * i9;
            *(float4*)dst = var;
        }
        __syncthreads();

        // ---- phase 2: 3x3 conv over 16 channels, 3 kd taps per thread ----
#pragma unroll 1
        for (int c4 = 0; c4 < 4; ++c4) {
            const float* w0 = wt + (coff + c4 * 4 + 0) * 27;   // wave-uniform -> s_load
            const float* w1 = wt + (coff + c4 * 4 + 1) * 27;
            const float* w2 = wt + (coff + c4 * 4 + 2) * 27;
            const float* w3 = wt + (coff + c4 * 4 + 3) * 27;
#pragma unroll
            for (int kh = 0; kh < 3; ++kh)
#pragma unroll
                for (int kw = 0; kw < 3; ++kw) {
                    int k9 = kh * 3 + kw;
                    float4 t4 = *(const float4*)&vsh[((ty + kh) * 18 + tx + kw) * CP2 + c4 * 4];
                    acc0 += t4.x * w0[k9]      + t4.y * w1[k9]      + t4.z * w2[k9]      + t4.w * w3[k9];
                    acc1 += t4.x * w0[9 + k9]  + t4.y * w1[9 + k9]  + t4.z * w2[9 + k9]  + t4.w * w3[9 + k9];
                    acc2 += t4.x * w0[18 + k9] + t4.y * w1[18 + k9] + t4.z * w2[18 + k9] + t4.w * w3[18 + k9];
                }
        }
        if (half == 0) __syncthreads();   // protect vsh before next half overwrites
    }

    int gy = tileY * 16 + ty, gx = tileX * 16 + tx;
    size_t pix = (size_t)gy * Ww + gx;
    size_t p0 = ((size_t)(b * 3 + 0) * Dd + d) * HW + pix;
    size_t p1 = ((size_t)(b * 3 + 1) * Dd + d) * HW + pix;
    size_t p2 = ((size_t)(b * 3 + 2) * Dd + d) * HW + pix;
    S[p0] = acc0; S[p1] = acc1; S[p2] = acc2;
}

// ---------------- K3: cost from S, softmax over D, depth + conf -------------
__global__ __launch_bounds__(256)
void k_post(const float* __restrict__ S, const float* __restrict__ dvals,
            float* __restrict__ out) {
    int gid = blockIdx.x * 256 + threadIdx.x;      // 0..B*HW-1
    int b = gid / HW;
    int pix = gid - b * HW;
    const float* S0 = S + ((size_t)(b * 3 + 0) * Dd) * HW + pix;
    const float* S1 = S + ((size_t)(b * 3 + 1) * Dd) * HW + pix;
    const float* S2 = S + ((size_t)(b * 3 + 2) * Dd) * HW + pix;
    float cost[Dd];
#pragma unroll
    for (int d = 0; d < Dd; ++d) {
        float cst = S1[(size_t)d * HW];
        if (d > 0)      cst += S0[(size_t)(d - 1) * HW];
        if (d < Dd - 1) cst += S2[(size_t)(d + 1) * HW];
        cost[d] = cst;
    }
    float m = cost[0];
#pragma unroll
    for (int d = 1; d < Dd; ++d) m = fmaxf(m, cost[d]);
    float sum = 0.f;
#pragma unroll
    for (int d = 0; d < Dd; ++d) { float e = expf(cost[d] - m); cost[d] = e; sum += e; }
    float inv = 1.0f / sum;
    float dep = 0.f, di = 0.f;
#pragma unroll
    for (int d = 0; d < Dd; ++d) {
        float pr = cost[d] * inv;
        dep += pr * dvals[b * Dd + d];
        di += pr * (float)d;
    }
    int didx = (int)di;
    didx = min(max(didx, 0), Dd - 1);
    float conf = 0.f;
#pragma unroll
    for (int d = 0; d < Dd; ++d)
        conf += ((d >= didx - 1) && (d <= didx + 2)) ? cost[d] : 0.f;
    conf *= inv;
    out[gid] = dep;
    out[Bb * HW + gid] = conf;
}

// ---------------- launch ----------------------------------------------------
extern "C" void kernel_launch(void* const* d_in, const int* in_sizes, int n_in,
                              void* d_out, int out_size, void* d_ws, size_t ws_size,
                              hipStream_t stream) {
    const float* features = (const float*)d_in[0];   // (V,B,C,H,W)
    const float* pm       = (const float*)d_in[1];   // (B,V,4,4)
    const float* dvals    = (const float*)d_in[2];   // (B,D)
    const float* reg_w    = (const float*)d_in[4];   // (1,C,3,3,3)
    float* outp = (float*)d_out;

    char* ws = (char*)d_ws;
    float* featT = (float*)ws;                                   // V*B*H*W*C floats
    size_t featT_bytes = (size_t)Vv * Bb * Hh * Ww * Cc * sizeof(float);
    float* P = (float*)(ws + featT_bytes);                       // 48 floats
    float* S = (float*)(ws + featT_bytes + 512);                 // B*3*D*H*W floats

    k_proj<<<1, 64, 0, stream>>>(pm, P);
    k_transpose<<<Vv * Bb * Hh, 256, 0, stream>>>(features, featT);
    k_main<<<dim3(80, Dd, Bb), 256, 0, stream>>>(featT, P, dvals, reg_w, S);
    k_post<<<(Bb * HW) / 256, 256, 0, stream>>>(S, dvals, outp);
}

// Round 7
// 189.859 us; speedup vs baseline: 3.1433x; 1.1717x over previous
//
#include <hip/hip_runtime.h>
#include <hip/hip_bf16.h>
#include <hip/hip_fp16.h>

#define Hh 128
#define Ww 160
#define Cc 32
#define Dd 48
#define Bb 2
#define Vv 3
#define HW (Hh*Ww)
#define VS 40    // vsh channel stride in ushorts (32 ch + 8 pad -> 80 B/slot, 16B-aligned reads)

typedef short bf16x8 __attribute__((ext_vector_type(8)));
typedef float f32x4 __attribute__((ext_vector_type(4)));

// ---- K0: proj matrices (threads 0..3) + bf16 MFMA B-fragment table (all 64) ----
// Bfr[tap][lane] = 8 bf16: w[kd=lane&15][c=(lane>>4)*8+j][tap], zero for kd>=3.
__global__ void k_proj(const float* __restrict__ pm, const float* __restrict__ wt,
                       float* __restrict__ P, ushort* __restrict__ Bfr) {
    int t = threadIdx.x;
    if (t < Bb * (Vv - 1)) {
        int b = t >> 1;
        int v = (t & 1) + 1;
        const float* ref = pm + (b * Vv + 0) * 16;
        const float* src = pm + (b * Vv + v) * 16;
        float A[4][8];
        for (int i = 0; i < 4; ++i)
            for (int j = 0; j < 4; ++j) {
                A[i][j] = ref[i * 4 + j];
                A[i][4 + j] = (i == j) ? 1.0f : 0.0f;
            }
        for (int col = 0; col < 4; ++col) {
            int piv = col;
            for (int r = col + 1; r < 4; ++r)
                if (fabsf(A[r][col]) > fabsf(A[piv][col])) piv = r;
            if (piv != col)
                for (int j = 0; j < 8; ++j) { float tmp = A[col][j]; A[col][j] = A[piv][j]; A[piv][j] = tmp; }
            float inv = 1.0f / A[col][col];
            for (int j = 0; j < 8; ++j) A[col][j] *= inv;
            for (int r = 0; r < 4; ++r) {
                if (r == col) continue;
                float f = A[r][col];
                for (int j = 0; j < 8; ++j) A[r][j] -= f * A[col][j];
            }
        }
        float Pm[3][4];
        for (int i = 0; i < 3; ++i)
            for (int j = 0; j < 4; ++j) {
                float s = 0.f;
                for (int k = 0; k < 4; ++k) s += src[i * 4 + k] * A[k][4 + j];
                Pm[i][j] = s;
            }
        float* o = P + t * 12;
        o[0] = Pm[0][0]; o[1] = Pm[0][1]; o[2] = Pm[0][2];
        o[3] = Pm[1][0]; o[4] = Pm[1][1]; o[5] = Pm[1][2];
        o[6] = Pm[2][0]; o[7] = Pm[2][1]; o[8] = Pm[2][2];
        o[9] = Pm[0][3]; o[10] = Pm[1][3]; o[11] = Pm[2][3];
    }
    // B-fragment table
    int kd = t & 15, q = t >> 4;
    for (int tap = 0; tap < 9; ++tap) {
        ushort vals[8];
        for (int j = 0; j < 8; ++j) {
            float w = (kd < 3) ? wt[(q * 8 + j) * 27 + kd * 9 + tap] : 0.f;
            __hip_bfloat16 h = __float2bfloat16(w);
            vals[j] = *(ushort*)&h;
        }
        ushort* dst = Bfr + (tap * 64 + t) * 8;
        for (int j = 0; j < 8; ++j) dst[j] = vals[j];
    }
}

// ---------------- K1: transpose (v,b,c,h,w) -> (v,b,h,w,c) ------------------
__global__ void k_transpose(const float* __restrict__ f, float* __restrict__ featT) {
    __shared__ float t[Cc][Ww + 1];
    int slice = blockIdx.x;          // vb*H + y
    int vb = slice / Hh, y = slice % Hh;
    const float* src = f + (size_t)vb * Cc * HW + (size_t)y * Ww;
    float* dst = featT + ((size_t)vb * Hh + y) * Ww * Cc;
    for (int i = threadIdx.x; i < Cc * Ww; i += 256) {
        int c = i / Ww, x = i - c * Ww;
        t[c][x] = src[(size_t)c * HW + x];
    }
    __syncthreads();
    for (int i = threadIdx.x; i < Cc * Ww; i += 256) {
        int x = i >> 5, c = i & 31;
        dst[i] = t[c][x];
    }
}

// ---------------- K2: variance tile (bf16) + MFMA 3x3 conv -> S -------------
// R6 structure (LDS coord cache -> no register spill) + R7: vsh in bf16 full
// 32 ch (single pass, one barrier pair) and the channel contraction done by
// v_mfma_f32_16x16x32_bf16: per wave 4 row-groups x 9 taps = 36 MFMA replace
// 864 scalar FMAs. A[m=lane&15][k=quad*8+j] (pixel-x, channel), B from the
// k_proj-packed table, D col=lane&15=kd row=quad*4+reg=pixel-x.
__global__ __launch_bounds__(256, 4)
void k_main(const float* __restrict__ featT, const float* __restrict__ P,
            const float* __restrict__ dvals, const ushort* __restrict__ Bfr,
            float* __restrict__ S) {
    __shared__ ushort vsh[324 * VS];          // 25.9 KB bf16 variance tile (32 ch)
    __shared__ unsigned int offs[324 * 4];    // 5.2 KB packed corner pixel idx
    __shared__ unsigned int wgts[324 * 4];    // 5.2 KB packed fp16 weights
    __shared__ float rt[24];
    const int tid = threadIdx.x;
    const int b = blockIdx.z, d = blockIdx.y;
    const int tileY = blockIdx.x / 10, tileX = blockIdx.x - (blockIdx.x / 10) * 10;

    if (tid < 24) rt[tid] = P[b * 24 + tid];
    const float depth = dvals[b * Dd + d];
    __syncthreads();

    // ---- stage A: bilinear coords for all 324 slots, once per block ----
#pragma unroll 1
    for (int p = tid; p < 324; p += 256) {
        int pyt = p / 18, pxt = p - pyt * 18;
        int gy = tileY * 16 + pyt - 1, gx = tileX * 16 + pxt - 1;
        if ((unsigned)gy >= (unsigned)Hh || (unsigned)gx >= (unsigned)Ww) continue;
#pragma unroll
        for (int vi = 0; vi < 2; ++vi) {
            const float* M = &rt[vi * 12];
            float fgx = (float)gx, fgy = (float)gy;
            float rx = M[0] * fgx + M[1] * fgy + M[2];
            float ry = M[3] * fgx + M[4] * fgy + M[5];
            float rz = M[6] * fgx + M[7] * fgy + M[8];
            float X = rx * depth + M[9];
            float Y = ry * depth + M[10];
            float Z = rz * depth + M[11];
            float z = (fabsf(Z) < 1e-6f) ? 1e-6f : Z;
            float u = X / z, vv = Y / z;
            float x0f = floorf(u), y0f = floorf(vv);
            float fx = u - x0f, fy = vv - y0f;
            int x0 = (int)x0f, y0 = (int)y0f;
            int x1 = x0 + 1, y1 = y0 + 1;
            bool vx0 = (x0 >= 0) && (x0 <= Ww - 1);
            bool vx1 = (x1 >= 0) && (x1 <= Ww - 1);
            bool vy0 = (y0 >= 0) && (y0 <= Hh - 1);
            bool vy1 = (y1 >= 0) && (y1 <= Hh - 1);
            int xc0 = min(max(x0, 0), Ww - 1), xc1 = min(max(x1, 0), Ww - 1);
            int yc0 = min(max(y0, 0), Hh - 1), yc1 = min(max(y1, 0), Hh - 1);
            unsigned int p00 = (unsigned)(yc0 * Ww + xc0);
            unsigned int p01 = (unsigned)(yc0 * Ww + xc1);
            unsigned int p10 = (unsigned)(yc1 * Ww + xc0);
            unsigned int p11 = (unsigned)(yc1 * Ww + xc1);
            float w0 = (vx0 && vy0) ? (1.f - fx) * (1.f - fy) : 0.f;
            float w1 = (vx1 && vy0) ? fx * (1.f - fy) : 0.f;
            float w2 = (vx0 && vy1) ? (1.f - fx) * fy : 0.f;
            float w3 = (vx1 && vy1) ? fx * fy : 0.f;
            offs[p * 4 + vi * 2 + 0] = p00 | (p01 << 16);
            offs[p * 4 + vi * 2 + 1] = p10 | (p11 << 16);
            __half2 ha = __floats2half2_rn(w0, w1);
            __half2 hb = __floats2half2_rn(w2, w3);
            wgts[p * 4 + vi * 2 + 0] = *(unsigned int*)&ha;
            wgts[p * 4 + vi * 2 + 1] = *(unsigned int*)&hb;
        }
    }
    __syncthreads();

    const float* b1 = featT + (size_t)(1 * Bb + b) * HW * Cc;
    const float* b2 = featT + (size_t)(2 * Bb + b) * HW * Cc;
    const float* br = featT + (size_t)b * HW * Cc;

    // ---- stage B: gather items (slot, c4-quad 0..7): 2592 items, bf16 out ----
#pragma unroll 1
    for (int i = tid; i < 2592; i += 256) {
        int p = i >> 3, c4 = i & 7;
        int pyt = p / 18, pxt = p - pyt * 18;
        int gy = tileY * 16 + pyt - 1, gx = tileX * 16 + pxt - 1;
        ushort* dst = &vsh[p * VS + c4 * 4];
        if ((unsigned)gy >= (unsigned)Hh || (unsigned)gx >= (unsigned)Ww) {
            *(uint2*)dst = make_uint2(0u, 0u);
            continue;
        }
        uint4 oo = *(const uint4*)&offs[p * 4];
        uint4 wwp = *(const uint4*)&wgts[p * 4];
        int cb = c4 * 4;
        int o00 = (int)(oo.x & 0xffffu) * Cc + cb;
        int o01 = (int)(oo.x >> 16)     * Cc + cb;
        int o10 = (int)(oo.y & 0xffffu) * Cc + cb;
        int o11 = (int)(oo.y >> 16)     * Cc + cb;
        int o20 = (int)(oo.z & 0xffffu) * Cc + cb;
        int o21 = (int)(oo.z >> 16)     * Cc + cb;
        int o30 = (int)(oo.w & 0xffffu) * Cc + cb;
        int o31 = (int)(oo.w >> 16)     * Cc + cb;
        float2 wa = __half22float2(*(__half2*)&wwp.x);  // v0: w0,w1
        float2 wb = __half22float2(*(__half2*)&wwp.y);  // v0: w2,w3
        float2 wc = __half22float2(*(__half2*)&wwp.z);  // v1: w0,w1
        float2 wd = __half22float2(*(__half2*)&wwp.w);  // v1: w2,w3
        float4 r  = *(const float4*)(br + (size_t)(gy * Ww + gx) * Cc + cb);
        float4 c0 = *(const float4*)(b1 + o00);
        float4 c1 = *(const float4*)(b1 + o01);
        float4 c2 = *(const float4*)(b1 + o10);
        float4 c3 = *(const float4*)(b1 + o11);
        float4 e0 = *(const float4*)(b2 + o20);
        float4 e1 = *(const float4*)(b2 + o21);
        float4 e2 = *(const float4*)(b2 + o30);
        float4 e3 = *(const float4*)(b2 + o31);
        float4 s1, s2, sum, sq, var;
        s1.x = wa.x * c0.x + wa.y * c1.x + wb.x * c2.x + wb.y * c3.x;
        s1.y = wa.x * c0.y + wa.y * c1.y + wb.x * c2.y + wb.y * c3.y;
        s1.z = wa.x * c0.z + wa.y * c1.z + wb.x * c2.z + wb.y * c3.z;
        s1.w = wa.x * c0.w + wa.y * c1.w + wb.x * c2.w + wb.y * c3.w;
        s2.x = wc.x * e0.x + wc.y * e1.x + wd.x * e2.x + wd.y * e3.x;
        s2.y = wc.x * e0.y + wc.y * e1.y + wd.x * e2.y + wd.y * e3.y;
        s2.z = wc.x * e0.z + wc.y * e1.z + wd.x * e2.z + wd.y * e3.z;
        s2.w = wc.x * e0.w + wc.y * e1.w + wd.x * e2.w + wd.y * e3.w;
        const float i3 = 1.0f / 3.0f, i9 = 1.0f / 9.0f;
        sum.x = r.x + s1.x + s2.x; sum.y = r.y + s1.y + s2.y;
        sum.z = r.z + s1.z + s2.z; sum.w = r.w + s1.w + s2.w;
        sq.x = r.x * r.x + s1.x * s1.x + s2.x * s2.x;
        sq.y = r.y * r.y + s1.y * s1.y + s2.y * s2.y;
        sq.z = r.z * r.z + s1.z * s1.z + s2.z * s2.z;
        sq.w = r.w * r.w + s1.w * s1.w + s2.w * s2.w;
        var.x = sq.x * i3 - sum.x * sum.x * i9;
        var.y = sq.y * i3 - sum.y * sum.y * i9;
        var.z = sq.z * i3 - sum.z * sum.z * i9;
        var.w = sq.w * i3 - sum.w * sum.w * i9;
        __hip_bfloat162 h0 = __float22bfloat162_rn(make_float2(var.x, var.y));
        __hip_bfloat162 h1 = __float22bfloat162_rn(make_float2(var.z, var.w));
        *(uint2*)dst = make_uint2(*(unsigned int*)&h0, *(unsigned int*)&h1);
    }
    __syncthreads();

    // ---- phase 2: MFMA conv. Wave covers 4 row-groups of 16 pixels. ----
    const int lane = tid & 63;
    const int wave = tid >> 6;
    const int q = lane >> 4;      // k-chunk selector (channels q*8..+7) / D row quad
    const int n = lane & 15;      // A: pixel-x ; B/D: kd column
#pragma unroll 1
    for (int rr = 0; rr < 4; ++rr) {
        int row = wave * 4 + rr;            // ty of this 16-pixel row-group
        f32x4 acc = {0.f, 0.f, 0.f, 0.f};
#pragma unroll
        for (int tap = 0; tap < 9; ++tap) {
            int kh = tap / 3, kw = tap - 3 * (tap / 3);
            union { uint4 u; bf16x8 v; } A, Bf;
            A.u  = *(const uint4*)&vsh[((row + kh) * 18 + n + kw) * VS + q * 8];
            Bf.u = *(const uint4*)(Bfr + ((tap * 64 + lane) << 3));
            acc = __builtin_amdgcn_mfma_f32_16x16x32_bf16(A.v, Bf.v, acc, 0, 0, 0);
        }
        if (n < 3) {   // lane holds D[pixel-x = q*4+reg][kd = n]
            int gy = tileY * 16 + row;
            int gxb = tileX * 16 + q * 4;
            float4 o = make_float4(acc[0], acc[1], acc[2], acc[3]);
            *(float4*)&S[((size_t)(b * 3 + n) * Dd + d) * HW + (size_t)gy * Ww + gxb] = o;
        }
    }
}

// ---------------- K3: cost from S, softmax over D, depth + conf -------------
__global__ __launch_bounds__(256)
void k_post(const float* __restrict__ S, const float* __restrict__ dvals,
            float* __restrict__ out) {
    int gid = blockIdx.x * 256 + threadIdx.x;      // 0..B*HW-1
    int b = gid / HW;
    int pix = gid - b * HW;
    const float* S0 = S + ((size_t)(b * 3 + 0) * Dd) * HW + pix;
    const float* S1 = S + ((size_t)(b * 3 + 1) * Dd) * HW + pix;
    const float* S2 = S + ((size_t)(b * 3 + 2) * Dd) * HW + pix;
    float cost[Dd];
#pragma unroll
    for (int d = 0; d < Dd; ++d) {
        float cst = S1[(size_t)d * HW];
        if (d > 0)      cst += S0[(size_t)(d - 1) * HW];
        if (d < Dd - 1) cst += S2[(size_t)(d + 1) * HW];
        cost[d] = cst;
    }
    float m = cost[0];
#pragma unroll
    for (int d = 1; d < Dd; ++d) m = fmaxf(m, cost[d]);
    float sum = 0.f;
#pragma unroll
    for (int d = 0; d < Dd; ++d) { float e = expf(cost[d] - m); cost[d] = e; sum += e; }
    float inv = 1.0f / sum;
    float dep = 0.f, di = 0.f;
#pragma unroll
    for (int d = 0; d < Dd; ++d) {
        float pr = cost[d] * inv;
        dep += pr * dvals[b * Dd + d];
        di += pr * (float)d;
    }
    int didx = (int)di;
    didx = min(max(didx, 0), Dd - 1);
    float conf = 0.f;
#pragma unroll
    for (int d = 0; d < Dd; ++d)
        conf += ((d >= didx - 1) && (d <= didx + 2)) ? cost[d] : 0.f;
    conf *= inv;
    out[gid] = dep;
    out[Bb * HW + gid] = conf;
}

// ---------------- launch ----------------------------------------------------
extern "C" void kernel_launch(void* const* d_in, const int* in_sizes, int n_in,
                              void* d_out, int out_size, void* d_ws, size_t ws_size,
                              hipStream_t stream) {
    const float* features = (const float*)d_in[0];   // (V,B,C,H,W)
    const float* pm       = (const float*)d_in[1];   // (B,V,4,4)
    const float* dvals    = (const float*)d_in[2];   // (B,D)
    const float* reg_w    = (const float*)d_in[4];   // (1,C,3,3,3)
    float* outp = (float*)d_out;

    char* ws = (char*)d_ws;
    float* featT = (float*)ws;                                   // V*B*H*W*C floats
    size_t featT_bytes = (size_t)Vv * Bb * Hh * Ww * Cc * sizeof(float);
    float* P = (float*)(ws + featT_bytes);                       // 48 floats
    float* S = (float*)(ws + featT_bytes + 512);                 // B*3*D*H*W floats
    size_t S_bytes = (size_t)Bb * 3 * Dd * HW * sizeof(float);
    ushort* Bfr = (ushort*)(ws + featT_bytes + 512 + S_bytes);   // 9*64*8 bf16

    k_proj<<<1, 64, 0, stream>>>(pm, reg_w, P, Bfr);
    k_transpose<<<Vv * Bb * Hh, 256, 0, stream>>>(features, featT);
    k_main<<<dim3(80, Dd, Bb), 256, 0, stream>>>(featT, P, dvals, Bfr, S);
    k_post<<<(Bb * HW) / 256, 256, 0, stream>>>(S, dvals, outp);
}

// Round 8
// 155.005 us; speedup vs baseline: 3.8501x; 1.2249x over previous
//
#include <hip/hip_runtime.h>
#include <hip/hip_bf16.h>
#include <hip/hip_fp16.h>

#define Hh 128
#define Ww 160
#define Cc 32
#define Dd 48
#define Bb 2
#define Vv 3
#define HW (Hh*Ww)
#define VS 40    // vsh channel stride in f16 units (32 ch + 8 pad -> 80 B/slot)

typedef _Float16 f16x8 __attribute__((ext_vector_type(8)));
typedef float f32x4 __attribute__((ext_vector_type(4)));

// ---- K0: proj matrices (threads 0..3) + f16 MFMA B-fragment table (all 64) ----
// Bfr[tap][lane] = 8 f16: w[kd=lane&15][c=(lane>>4)*8+j][tap], zero for kd>=3.
__global__ void k_proj(const float* __restrict__ pm, const float* __restrict__ wt,
                       float* __restrict__ P, ushort* __restrict__ Bfr) {
    int t = threadIdx.x;
    if (t < Bb * (Vv - 1)) {
        int b = t >> 1;
        int v = (t & 1) + 1;
        const float* ref = pm + (b * Vv + 0) * 16;
        const float* src = pm + (b * Vv + v) * 16;
        float A[4][8];
        for (int i = 0; i < 4; ++i)
            for (int j = 0; j < 4; ++j) {
                A[i][j] = ref[i * 4 + j];
                A[i][4 + j] = (i == j) ? 1.0f : 0.0f;
            }
        for (int col = 0; col < 4; ++col) {
            int piv = col;
            for (int r = col + 1; r < 4; ++r)
                if (fabsf(A[r][col]) > fabsf(A[piv][col])) piv = r;
            if (piv != col)
                for (int j = 0; j < 8; ++j) { float tmp = A[col][j]; A[col][j] = A[piv][j]; A[piv][j] = tmp; }
            float inv = 1.0f / A[col][col];
            for (int j = 0; j < 8; ++j) A[col][j] *= inv;
            for (int r = 0; r < 4; ++r) {
                if (r == col) continue;
                float f = A[r][col];
                for (int j = 0; j < 8; ++j) A[r][j] -= f * A[col][j];
            }
        }
        float Pm[3][4];
        for (int i = 0; i < 3; ++i)
            for (int j = 0; j < 4; ++j) {
                float s = 0.f;
                for (int k = 0; k < 4; ++k) s += src[i * 4 + k] * A[k][4 + j];
                Pm[i][j] = s;
            }
        float* o = P + t * 12;
        o[0] = Pm[0][0]; o[1] = Pm[0][1]; o[2] = Pm[0][2];
        o[3] = Pm[1][0]; o[4] = Pm[1][1]; o[5] = Pm[1][2];
        o[6] = Pm[2][0]; o[7] = Pm[2][1]; o[8] = Pm[2][2];
        o[9] = Pm[0][3]; o[10] = Pm[1][3]; o[11] = Pm[2][3];
    }
    // B-fragment table (f16)
    int kd = t & 15, q = t >> 4;
    for (int tap = 0; tap < 9; ++tap) {
        ushort* dst = Bfr + (tap * 64 + t) * 8;
        for (int j = 0; j < 8; ++j) {
            float w = (kd < 3) ? wt[(q * 8 + j) * 27 + kd * 9 + tap] : 0.f;
            __half h = __float2half(w);
            dst[j] = *(ushort*)&h;
        }
    }
}

// ---------------- K1: transpose (v,b,c,h,w) fp32 -> (v,b,h,w,c) fp16 --------
__global__ void k_transpose(const float* __restrict__ f, ushort* __restrict__ featT) {
    __shared__ float t[Cc][Ww + 1];
    int slice = blockIdx.x;          // vb*H + y
    int vb = slice / Hh, y = slice % Hh;
    const float* src = f + (size_t)vb * Cc * HW + (size_t)y * Ww;
    ushort* dst = featT + ((size_t)vb * Hh + y) * Ww * Cc;
    for (int i = threadIdx.x; i < Cc * Ww; i += 256) {
        int c = i / Ww, x = i - c * Ww;
        t[c][x] = src[(size_t)c * HW + x];
    }
    __syncthreads();
    // each thread packs 8 channels of one x -> one dwordx4 store
    for (int i = threadIdx.x; i < Ww * 4; i += 256) {
        int x = i >> 2, c8 = i & 3;
        union { uint4 u; ushort s[8]; } pk;
#pragma unroll
        for (int j = 0; j < 8; ++j) {
            __half h = __float2half(t[c8 * 8 + j][x]);
            pk.s[j] = *(ushort*)&h;
        }
        *(uint4*)&dst[x * Cc + c8 * 8] = pk.u;
    }
}

// ---------------- K2: f16 variance tile + f16 MFMA 3x3 conv -> S ------------
// R6 LDS coord cache (no reg spill) + R7 MFMA conv + R8: featT/vsh/math in
// fp16. Stage B items carry 8 channels per dwordx4 corner load (1296 items,
// half the loads) and use packed v_pk_fma_f16 (half the VALU).
__global__ __launch_bounds__(256, 4)
void k_main(const ushort* __restrict__ featT, const float* __restrict__ P,
            const float* __restrict__ dvals, const ushort* __restrict__ Bfr,
            float* __restrict__ S) {
    __shared__ ushort vsh[324 * VS];          // 25.9 KB f16 variance tile (32 ch)
    __shared__ unsigned int offs[324 * 4];    // 5.2 KB packed corner pixel idx
    __shared__ unsigned int wgts[324 * 4];    // 5.2 KB packed fp16 weights
    __shared__ float rt[24];
    const int tid = threadIdx.x;
    const int b = blockIdx.z, d = blockIdx.y;
    const int tileY = blockIdx.x / 10, tileX = blockIdx.x - (blockIdx.x / 10) * 10;

    if (tid < 24) rt[tid] = P[b * 24 + tid];
    const float depth = dvals[b * Dd + d];
    __syncthreads();

    // ---- stage A: bilinear coords for all 324 slots, once per block ----
#pragma unroll 1
    for (int p = tid; p < 324; p += 256) {
        int pyt = p / 18, pxt = p - pyt * 18;
        int gy = tileY * 16 + pyt - 1, gx = tileX * 16 + pxt - 1;
        if ((unsigned)gy >= (unsigned)Hh || (unsigned)gx >= (unsigned)Ww) continue;
#pragma unroll
        for (int vi = 0; vi < 2; ++vi) {
            const float* M = &rt[vi * 12];
            float fgx = (float)gx, fgy = (float)gy;
            float rx = M[0] * fgx + M[1] * fgy + M[2];
            float ry = M[3] * fgx + M[4] * fgy + M[5];
            float rz = M[6] * fgx + M[7] * fgy + M[8];
            float X = rx * depth + M[9];
            float Y = ry * depth + M[10];
            float Z = rz * depth + M[11];
            float z = (fabsf(Z) < 1e-6f) ? 1e-6f : Z;
            float u = X / z, vv = Y / z;
            float x0f = floorf(u), y0f = floorf(vv);
            float fx = u - x0f, fy = vv - y0f;
            int x0 = (int)x0f, y0 = (int)y0f;
            int x1 = x0 + 1, y1 = y0 + 1;
            bool vx0 = (x0 >= 0) && (x0 <= Ww - 1);
            bool vx1 = (x1 >= 0) && (x1 <= Ww - 1);
            bool vy0 = (y0 >= 0) && (y0 <= Hh - 1);
            bool vy1 = (y1 >= 0) && (y1 <= Hh - 1);
            int xc0 = min(max(x0, 0), Ww - 1), xc1 = min(max(x1, 0), Ww - 1);
            int yc0 = min(max(y0, 0), Hh - 1), yc1 = min(max(y1, 0), Hh - 1);
            unsigned int p00 = (unsigned)(yc0 * Ww + xc0);
            unsigned int p01 = (unsigned)(yc0 * Ww + xc1);
            unsigned int p10 = (unsigned)(yc1 * Ww + xc0);
            unsigned int p11 = (unsigned)(yc1 * Ww + xc1);
            float w0 = (vx0 && vy0) ? (1.f - fx) * (1.f - fy) : 0.f;
            float w1 = (vx1 && vy0) ? fx * (1.f - fy) : 0.f;
            float w2 = (vx0 && vy1) ? (1.f - fx) * fy : 0.f;
            float w3 = (vx1 && vy1) ? fx * fy : 0.f;
            offs[p * 4 + vi * 2 + 0] = p00 | (p01 << 16);
            offs[p * 4 + vi * 2 + 1] = p10 | (p11 << 16);
            __half2 ha = __floats2half2_rn(w0, w1);
            __half2 hb = __floats2half2_rn(w2, w3);
            wgts[p * 4 + vi * 2 + 0] = *(unsigned int*)&ha;
            wgts[p * 4 + vi * 2 + 1] = *(unsigned int*)&hb;
        }
    }
    __syncthreads();

    const ushort* b1 = featT + (size_t)(1 * Bb + b) * HW * Cc;
    const ushort* b2 = featT + (size_t)(2 * Bb + b) * HW * Cc;
    const ushort* br = featT + (size_t)b * HW * Cc;

    // ---- stage B: gather items (slot, c8 0..3): 1296 items, f16 math ----
#pragma unroll 1
    for (int i = tid; i < 1296; i += 256) {
        int p = i >> 2, c8 = i & 3;
        int pyt = p / 18, pxt = p - pyt * 18;
        int gy = tileY * 16 + pyt - 1, gx = tileX * 16 + pxt - 1;
        ushort* dst = &vsh[p * VS + c8 * 8];
        if ((unsigned)gy >= (unsigned)Hh || (unsigned)gx >= (unsigned)Ww) {
            *(uint4*)dst = make_uint4(0u, 0u, 0u, 0u);
            continue;
        }
        uint4 oo = *(const uint4*)&offs[p * 4];
        uint4 wwp = *(const uint4*)&wgts[p * 4];
        int cb = c8 * 8;
        int o00 = (int)(oo.x & 0xffffu) * Cc + cb;
        int o01 = (int)(oo.x >> 16)     * Cc + cb;
        int o10 = (int)(oo.y & 0xffffu) * Cc + cb;
        int o11 = (int)(oo.y >> 16)     * Cc + cb;
        int o20 = (int)(oo.z & 0xffffu) * Cc + cb;
        int o21 = (int)(oo.z >> 16)     * Cc + cb;
        int o30 = (int)(oo.w & 0xffffu) * Cc + cb;
        int o31 = (int)(oo.w >> 16)     * Cc + cb;
        __half2 hv0 = *(__half2*)&wwp.x;   // v0: (w0,w1)
        __half2 hv1 = *(__half2*)&wwp.y;   // v0: (w2,w3)
        __half2 hv2 = *(__half2*)&wwp.z;   // v1: (w0,w1)
        __half2 hv3 = *(__half2*)&wwp.w;   // v1: (w2,w3)
        __half2 w00 = __half2half2(__low2half(hv0)), w01 = __half2half2(__high2half(hv0));
        __half2 w02 = __half2half2(__low2half(hv1)), w03 = __half2half2(__high2half(hv1));
        __half2 w10 = __half2half2(__low2half(hv2)), w11 = __half2half2(__high2half(hv2));
        __half2 w12 = __half2half2(__low2half(hv3)), w13 = __half2half2(__high2half(hv3));
        union U { uint4 u; __half2 h[4]; };
        U R, C0, C1, C2, C3, E0, E1, E2, E3, V;
        R.u  = *(const uint4*)(br + (size_t)(gy * Ww + gx) * Cc + cb);
        C0.u = *(const uint4*)(b1 + o00);
        C1.u = *(const uint4*)(b1 + o01);
        C2.u = *(const uint4*)(b1 + o10);
        C3.u = *(const uint4*)(b1 + o11);
        E0.u = *(const uint4*)(b2 + o20);
        E1.u = *(const uint4*)(b2 + o21);
        E2.u = *(const uint4*)(b2 + o30);
        E3.u = *(const uint4*)(b2 + o31);
        const __half2 third2 = __float2half2_rn(1.0f / 3.0f);
#pragma unroll
        for (int k = 0; k < 4; ++k) {
            __half2 s1 = __hmul2(w00, C0.h[k]);
            s1 = __hfma2(w01, C1.h[k], s1);
            s1 = __hfma2(w02, C2.h[k], s1);
            s1 = __hfma2(w03, C3.h[k], s1);
            __half2 s2 = __hmul2(w10, E0.h[k]);
            s2 = __hfma2(w11, E1.h[k], s2);
            s2 = __hfma2(w12, E2.h[k], s2);
            s2 = __hfma2(w13, E3.h[k], s2);
            __half2 r = R.h[k];
            __half2 sum = __hadd2(__hadd2(r, s1), s2);
            __half2 sq = __hmul2(r, r);
            sq = __hfma2(s1, s1, sq);
            sq = __hfma2(s2, s2, sq);
            __half2 m = __hmul2(sum, third2);
            __half2 var = __hfma2(__hneg2(m), m, __hmul2(sq, third2));
            V.h[k] = var;
        }
        *(uint4*)dst = V.u;
    }
    __syncthreads();

    // ---- phase 2: f16 MFMA conv. Wave covers 4 row-groups of 16 pixels. ----
    const int lane = tid & 63;
    const int wave = tid >> 6;
    const int q = lane >> 4;      // k-chunk selector (channels q*8..+7) / D row quad
    const int n = lane & 15;      // A: pixel-x ; B/D: kd column
#pragma unroll 1
    for (int rr = 0; rr < 4; ++rr) {
        int row = wave * 4 + rr;            // ty of this 16-pixel row-group
        f32x4 acc = {0.f, 0.f, 0.f, 0.f};
#pragma unroll
        for (int tap = 0; tap < 9; ++tap) {
            int kh = tap / 3, kw = tap - 3 * (tap / 3);
            union { uint4 u; f16x8 v; } A, Bf;
            A.u  = *(const uint4*)&vsh[((row + kh) * 18 + n + kw) * VS + q * 8];
            Bf.u = *(const uint4*)(Bfr + ((tap * 64 + lane) << 3));
            acc = __builtin_amdgcn_mfma_f32_16x16x32_f16(A.v, Bf.v, acc, 0, 0, 0);
        }
        if (n < 3) {   // lane holds D[pixel-x = q*4+reg][kd = n]
            int gy = tileY * 16 + row;
            int gxb = tileX * 16 + q * 4;
            float4 o = make_float4(acc[0], acc[1], acc[2], acc[3]);
            *(float4*)&S[((size_t)(b * 3 + n) * Dd + d) * HW + (size_t)gy * Ww + gxb] = o;
        }
    }
}

// ---------------- K3: cost, softmax, depth + conf; 4 lanes-of-depth/pixel ---
// Wave = 16 pixels x 4 d-chunks (lane&15 = pixel -> coalesced loads; chunk
// partner lanes at xor 16/32 -> shfl reductions). 2560 waves device-wide.
__global__ __launch_bounds__(256)
void k_post(const float* __restrict__ S, const float* __restrict__ dvals,
            float* __restrict__ out) {
    const int tid = threadIdx.x;
    const int lane = tid & 63, wave = tid >> 6;
    const int q = lane >> 4;                        // d-chunk: d = q*12 + j
    const int pl = lane & 15;                       // pixel within group
    int pix_g = (blockIdx.x * 4 + wave) * 16 + pl;  // 0..B*HW-1
    int b = pix_g / HW;
    int pix = pix_g - b * HW;
    const float* S0 = S + ((size_t)(b * 3 + 0) * Dd) * HW + pix;
    const float* S1 = S + ((size_t)(b * 3 + 1) * Dd) * HW + pix;
    const float* S2 = S + ((size_t)(b * 3 + 2) * Dd) * HW + pix;
    const int d0 = q * 12;
    float cost[12];
#pragma unroll
    for (int j = 0; j < 12; ++j) {
        int dd = d0 + j;
        float cst = S1[(size_t)dd * HW];
        if (dd > 0)      cst += S0[(size_t)(dd - 1) * HW];
        if (dd < Dd - 1) cst += S2[(size_t)(dd + 1) * HW];
        cost[j] = cst;
    }
    float m = cost[0];
#pragma unroll
    for (int j = 1; j < 12; ++j) m = fmaxf(m, cost[j]);
    m = fmaxf(m, __shfl_xor(m, 16));
    m = fmaxf(m, __shfl_xor(m, 32));
    float sum = 0.f, dep = 0.f, di = 0.f;
#pragma unroll
    for (int j = 0; j < 12; ++j) {
        float e = __expf(cost[j] - m);
        cost[j] = e;
        sum += e;
        dep += e * dvals[b * Dd + d0 + j];
        di  += e * (float)(d0 + j);
    }
    sum += __shfl_xor(sum, 16); sum += __shfl_xor(sum, 32);
    dep += __shfl_xor(dep, 16); dep += __shfl_xor(dep, 32);
    di  += __shfl_xor(di, 16);  di  += __shfl_xor(di, 32);
    float inv = 1.0f / sum;
    di *= inv;
    int didx = (int)di;
    didx = min(max(didx, 0), Dd - 1);
    float win = 0.f;
#pragma unroll
    for (int j = 0; j < 12; ++j) {
        int dd = d0 + j;
        win += ((dd >= didx - 1) && (dd <= didx + 2)) ? cost[j] : 0.f;
    }
    win += __shfl_xor(win, 16); win += __shfl_xor(win, 32);
    if (q == 0) {
        out[pix_g] = dep * inv;
        out[Bb * HW + pix_g] = win * inv;
    }
}

// ---------------- launch ----------------------------------------------------
extern "C" void kernel_launch(void* const* d_in, const int* in_sizes, int n_in,
                              void* d_out, int out_size, void* d_ws, size_t ws_size,
                              hipStream_t stream) {
    const float* features = (const float*)d_in[0];   // (V,B,C,H,W)
    const float* pm       = (const float*)d_in[1];   // (B,V,4,4)
    const float* dvals    = (const float*)d_in[2];   // (B,D)
    const float* reg_w    = (const float*)d_in[4];   // (1,C,3,3,3)
    float* outp = (float*)d_out;

    char* ws = (char*)d_ws;
    ushort* featT = (ushort*)ws;                                 // V*B*H*W*C f16
    size_t featT_bytes = (size_t)Vv * Bb * Hh * Ww * Cc * sizeof(ushort);
    float* P = (float*)(ws + featT_bytes);                       // 48 floats
    float* S = (float*)(ws + featT_bytes + 512);                 // B*3*D*H*W floats
    size_t S_bytes = (size_t)Bb * 3 * Dd * HW * sizeof(float);
    ushort* Bfr = (ushort*)(ws + featT_bytes + 512 + S_bytes);   // 9*64*8 f16

    k_proj<<<1, 64, 0, stream>>>(pm, reg_w, P, Bfr);
    k_transpose<<<Vv * Bb * Hh, 256, 0, stream>>>(features, featT);
    k_main<<<dim3(80, Dd, Bb), 256, 0, stream>>>(featT, P, dvals, Bfr, S);
    k_post<<<(Bb * HW) / 64, 256, 0, stream>>>(S, dvals, outp);
}

// Round 9
// 152.629 us; speedup vs baseline: 3.9100x; 1.0156x over previous
//
#include <hip/hip_runtime.h>
#include <hip/hip_bf16.h>
#include <hip/hip_fp16.h>

#define Hh 128
#define Ww 160
#define Cc 32
#define Dd 48
#define Bb 2
#define Vv 3
#define HW (Hh*Ww)
#define VS 32    // vsh channel stride in f16 units: no pad; XOR swizzle keeps banks spread

typedef _Float16 f16x8 __attribute__((ext_vector_type(8)));
typedef float f32x4 __attribute__((ext_vector_type(4)));

// ---------------- K1: transpose (v,b,c,h,w) fp32 -> (v,b,h,w,c) fp16 --------
// Block 0 additionally computes proj matrices (threads 0..3) and the f16 MFMA
// B-fragment table Bfr[tap][lane] (threads 0..63): w[kd=lane&15][c=q*8+j][tap].
__global__ void k_transpose(const float* __restrict__ f, const float* __restrict__ pm,
                            const float* __restrict__ wt, ushort* __restrict__ featT,
                            float* __restrict__ P, ushort* __restrict__ Bfr) {
    __shared__ float t[Cc][Ww + 1];
    const int tid = threadIdx.x;
    if (blockIdx.x == 0 && tid < 64) {
        if (tid < Bb * (Vv - 1)) {
            int b = tid >> 1;
            int v = (tid & 1) + 1;
            const float* ref = pm + (b * Vv + 0) * 16;
            const float* src = pm + (b * Vv + v) * 16;
            float A[4][8];
            for (int i = 0; i < 4; ++i)
                for (int j = 0; j < 4; ++j) {
                    A[i][j] = ref[i * 4 + j];
                    A[i][4 + j] = (i == j) ? 1.0f : 0.0f;
                }
            for (int col = 0; col < 4; ++col) {
                int piv = col;
                for (int r = col + 1; r < 4; ++r)
                    if (fabsf(A[r][col]) > fabsf(A[piv][col])) piv = r;
                if (piv != col)
                    for (int j = 0; j < 8; ++j) { float tmp = A[col][j]; A[col][j] = A[piv][j]; A[piv][j] = tmp; }
                float inv = 1.0f / A[col][col];
                for (int j = 0; j < 8; ++j) A[col][j] *= inv;
                for (int r = 0; r < 4; ++r) {
                    if (r == col) continue;
                    float fct = A[r][col];
                    for (int j = 0; j < 8; ++j) A[r][j] -= fct * A[col][j];
                }
            }
            float Pm[3][4];
            for (int i = 0; i < 3; ++i)
                for (int j = 0; j < 4; ++j) {
                    float s = 0.f;
                    for (int k = 0; k < 4; ++k) s += src[i * 4 + k] * A[k][4 + j];
                    Pm[i][j] = s;
                }
            float* o = P + tid * 12;
            o[0] = Pm[0][0]; o[1] = Pm[0][1]; o[2] = Pm[0][2];
            o[3] = Pm[1][0]; o[4] = Pm[1][1]; o[5] = Pm[1][2];
            o[6] = Pm[2][0]; o[7] = Pm[2][1]; o[8] = Pm[2][2];
            o[9] = Pm[0][3]; o[10] = Pm[1][3]; o[11] = Pm[2][3];
        }
        int kd = tid & 15, q = tid >> 4;
        for (int tap = 0; tap < 9; ++tap) {
            ushort* dst = Bfr + (tap * 64 + tid) * 8;
            for (int j = 0; j < 8; ++j) {
                float w = (kd < 3) ? wt[(q * 8 + j) * 27 + kd * 9 + tap] : 0.f;
                __half h = __float2half(w);
                dst[j] = *(ushort*)&h;
            }
        }
    }
    int slice = blockIdx.x;          // vb*H + y
    int vb = slice / Hh, y = slice % Hh;
    const float* src = f + (size_t)vb * Cc * HW + (size_t)y * Ww;
    ushort* dst = featT + ((size_t)vb * Hh + y) * Ww * Cc;
    // float4 loads: 1280 vec-elems
    for (int i = tid; i < Cc * (Ww / 4); i += 256) {
        int c = i / (Ww / 4), x4 = (i - c * (Ww / 4)) * 4;
        float4 v = *(const float4*)(src + (size_t)c * HW + x4);
        t[c][x4] = v.x; t[c][x4 + 1] = v.y; t[c][x4 + 2] = v.z; t[c][x4 + 3] = v.w;
    }
    __syncthreads();
    // each thread packs 8 channels of one x -> one dwordx4 store
    for (int i = tid; i < Ww * 4; i += 256) {
        int x = i >> 2, c8 = i & 3;
        union { uint4 u; ushort s[8]; } pk;
#pragma unroll
        for (int j = 0; j < 8; ++j) {
            __half h = __float2half(t[c8 * 8 + j][x]);
            pk.s[j] = *(ushort*)&h;
        }
        *(uint4*)&dst[x * Cc + c8 * 8] = pk.u;
    }
}

// ---------------- K2: f16 variance tile + f16 MFMA 3x3 conv -> S ------------
// R6 LDS coord cache + R7 MFMA conv + R8 fp16 + R9: VS=32 with XOR chunk
// swizzle (chunk ^= slot&3, 16B-aligned) -> LDS 31.2 KB -> 5 blocks/CU
// (20 waves, was 16); Bfr fragments hoisted out of the rr loop.
__global__ __launch_bounds__(256, 5)
void k_main(const ushort* __restrict__ featT, const float* __restrict__ P,
            const float* __restrict__ dvals, const ushort* __restrict__ Bfr,
            float* __restrict__ S) {
    __shared__ ushort vsh[324 * VS];          // 20.7 KB f16 variance tile (32 ch)
    __shared__ unsigned int offs[324 * 4];    // 5.2 KB packed corner pixel idx
    __shared__ unsigned int wgts[324 * 4];    // 5.2 KB packed fp16 weights
    __shared__ float rt[24];
    const int tid = threadIdx.x;
    const int b = blockIdx.z, d = blockIdx.y;
    const int tileY = blockIdx.x / 10, tileX = blockIdx.x - (blockIdx.x / 10) * 10;

    if (tid < 24) rt[tid] = P[b * 24 + tid];
    const float depth = dvals[b * Dd + d];
    __syncthreads();

    // ---- stage A: bilinear coords for all 324 slots, once per block ----
#pragma unroll 1
    for (int p = tid; p < 324; p += 256) {
        int pyt = p / 18, pxt = p - pyt * 18;
        int gy = tileY * 16 + pyt - 1, gx = tileX * 16 + pxt - 1;
        if ((unsigned)gy >= (unsigned)Hh || (unsigned)gx >= (unsigned)Ww) continue;
#pragma unroll
        for (int vi = 0; vi < 2; ++vi) {
            const float* M = &rt[vi * 12];
            float fgx = (float)gx, fgy = (float)gy;
            float rx = M[0] * fgx + M[1] * fgy + M[2];
            float ry = M[3] * fgx + M[4] * fgy + M[5];
            float rz = M[6] * fgx + M[7] * fgy + M[8];
            float X = rx * depth + M[9];
            float Y = ry * depth + M[10];
            float Z = rz * depth + M[11];
            float z = (fabsf(Z) < 1e-6f) ? 1e-6f : Z;
            float u = X / z, vv = Y / z;
            float x0f = floorf(u), y0f = floorf(vv);
            float fx = u - x0f, fy = vv - y0f;
            int x0 = (int)x0f, y0 = (int)y0f;
            int x1 = x0 + 1, y1 = y0 + 1;
            bool vx0 = (x0 >= 0) && (x0 <= Ww - 1);
            bool vx1 = (x1 >= 0) && (x1 <= Ww - 1);
            bool vy0 = (y0 >= 0) && (y0 <= Hh - 1);
            bool vy1 = (y1 >= 0) && (y1 <= Hh - 1);
            int xc0 = min(max(x0, 0), Ww - 1), xc1 = min(max(x1, 0), Ww - 1);
            int yc0 = min(max(y0, 0), Hh - 1), yc1 = min(max(y1, 0), Hh - 1);
            unsigned int p00 = (unsigned)(yc0 * Ww + xc0);
            unsigned int p01 = (unsigned)(yc0 * Ww + xc1);
            unsigned int p10 = (unsigned)(yc1 * Ww + xc0);
            unsigned int p11 = (unsigned)(yc1 * Ww + xc1);
            float w0 = (vx0 && vy0) ? (1.f - fx) * (1.f - fy) : 0.f;
            float w1 = (vx1 && vy0) ? fx * (1.f - fy) : 0.f;
            float w2 = (vx0 && vy1) ? (1.f - fx) * fy : 0.f;
            float w3 = (vx1 && vy1) ? fx * fy : 0.f;
            offs[p * 4 + vi * 2 + 0] = p00 | (p01 << 16);
            offs[p * 4 + vi * 2 + 1] = p10 | (p11 << 16);
            __half2 ha = __floats2half2_rn(w0, w1);
            __half2 hb = __floats2half2_rn(w2, w3);
            wgts[p * 4 + vi * 2 + 0] = *(unsigned int*)&ha;
            wgts[p * 4 + vi * 2 + 1] = *(unsigned int*)&hb;
        }
    }
    __syncthreads();

    const ushort* b1 = featT + (size_t)(1 * Bb + b) * HW * Cc;
    const ushort* b2 = featT + (size_t)(2 * Bb + b) * HW * Cc;
    const ushort* br = featT + (size_t)b * HW * Cc;

    // ---- stage B: gather items (slot, c8 0..3): 1296 items, f16 math ----
#pragma unroll 1
    for (int i = tid; i < 1296; i += 256) {
        int p = i >> 2, c8 = i & 3;
        int pyt = p / 18, pxt = p - pyt * 18;
        int gy = tileY * 16 + pyt - 1, gx = tileX * 16 + pxt - 1;
        ushort* dst = &vsh[p * VS + (c8 ^ (p & 3)) * 8];   // XOR bank swizzle
        if ((unsigned)gy >= (unsigned)Hh || (unsigned)gx >= (unsigned)Ww) {
            *(uint4*)dst = make_uint4(0u, 0u, 0u, 0u);
            continue;
        }
        uint4 oo = *(const uint4*)&offs[p * 4];
        uint4 wwp = *(const uint4*)&wgts[p * 4];
        int cb = c8 * 8;
        int o00 = (int)(oo.x & 0xffffu) * Cc + cb;
        int o01 = (int)(oo.x >> 16)     * Cc + cb;
        int o10 = (int)(oo.y & 0xffffu) * Cc + cb;
        int o11 = (int)(oo.y >> 16)     * Cc + cb;
        int o20 = (int)(oo.z & 0xffffu) * Cc + cb;
        int o21 = (int)(oo.z >> 16)     * Cc + cb;
        int o30 = (int)(oo.w & 0xffffu) * Cc + cb;
        int o31 = (int)(oo.w >> 16)     * Cc + cb;
        __half2 hv0 = *(__half2*)&wwp.x;   // v0: (w0,w1)
        __half2 hv1 = *(__half2*)&wwp.y;   // v0: (w2,w3)
        __half2 hv2 = *(__half2*)&wwp.z;   // v1: (w0,w1)
        __half2 hv3 = *(__half2*)&wwp.w;   // v1: (w2,w3)
        __half2 w00 = __half2half2(__low2half(hv0)), w01 = __half2half2(__high2half(hv0));
        __half2 w02 = __half2half2(__low2half(hv1)), w03 = __half2half2(__high2half(hv1));
        __half2 w10 = __half2half2(__low2half(hv2)), w11 = __half2half2(__high2half(hv2));
        __half2 w12 = __half2half2(__low2half(hv3)), w13 = __half2half2(__high2half(hv3));
        union U { uint4 u; __half2 h[4]; };
        U R, C0, C1, C2, C3, E0, E1, E2, E3, V;
        R.u  = *(const uint4*)(br + (size_t)(gy * Ww + gx) * Cc + cb);
        C0.u = *(const uint4*)(b1 + o00);
        C1.u = *(const uint4*)(b1 + o01);
        C2.u = *(const uint4*)(b1 + o10);
        C3.u = *(const uint4*)(b1 + o11);
        E0.u = *(const uint4*)(b2 + o20);
        E1.u = *(const uint4*)(b2 + o21);
        E2.u = *(const uint4*)(b2 + o30);
        E3.u = *(const uint4*)(b2 + o31);
        const __half2 third2 = __float2half2_rn(1.0f / 3.0f);
#pragma unroll
        for (int k = 0; k < 4; ++k) {
            __half2 s1 = __hmul2(w00, C0.h[k]);
            s1 = __hfma2(w01, C1.h[k], s1);
            s1 = __hfma2(w02, C2.h[k], s1);
            s1 = __hfma2(w03, C3.h[k], s1);
            __half2 s2 = __hmul2(w10, E0.h[k]);
            s2 = __hfma2(w11, E1.h[k], s2);
            s2 = __hfma2(w12, E2.h[k], s2);
            s2 = __hfma2(w13, E3.h[k], s2);
            __half2 r = R.h[k];
            __half2 sum = __hadd2(__hadd2(r, s1), s2);
            __half2 sq = __hmul2(r, r);
            sq = __hfma2(s1, s1, sq);
            sq = __hfma2(s2, s2, sq);
            __half2 m = __hmul2(sum, third2);
            __half2 var = __hfma2(__hneg2(m), m, __hmul2(sq, third2));
            V.h[k] = var;
        }
        *(uint4*)dst = V.u;
    }
    __syncthreads();

    // ---- phase 2: f16 MFMA conv. Wave covers 4 row-groups of 16 pixels. ----
    const int lane = tid & 63;
    const int wave = tid >> 6;
    const int q = lane >> 4;      // k-chunk selector (channels q*8..+7) / D row quad
    const int n = lane & 15;      // A: pixel-x ; B/D: kd column
    uint4 bf[9];
#pragma unroll
    for (int tap = 0; tap < 9; ++tap)
        bf[tap] = *(const uint4*)(Bfr + ((tap * 64 + lane) << 3));
#pragma unroll 1
    for (int rr = 0; rr < 4; ++rr) {
        int row = wave * 4 + rr;            // ty of this 16-pixel row-group
        f32x4 acc = {0.f, 0.f, 0.f, 0.f};
#pragma unroll
        for (int tap = 0; tap < 9; ++tap) {
            int kh = tap / 3, kw = tap - 3 * (tap / 3);
            int slot = (row + kh) * 18 + n + kw;
            union { uint4 u; f16x8 v; } A, Bf;
            A.u  = *(const uint4*)&vsh[slot * VS + (q ^ (slot & 3)) * 8];
            Bf.u = bf[tap];
            acc = __builtin_amdgcn_mfma_f32_16x16x32_f16(A.v, Bf.v, acc, 0, 0, 0);
        }
        if (n < 3) {   // lane holds D[pixel-x = q*4+reg][kd = n]
            int gy = tileY * 16 + row;
            int gxb = tileX * 16 + q * 4;
            float4 o = make_float4(acc[0], acc[1], acc[2], acc[3]);
            *(float4*)&S[((size_t)(b * 3 + n) * Dd + d) * HW + (size_t)gy * Ww + gxb] = o;
        }
    }
}

// ---------------- K3: cost, softmax, depth + conf; 4 lanes-of-depth/pixel ---
__global__ __launch_bounds__(256)
void k_post(const float* __restrict__ S, const float* __restrict__ dvals,
            float* __restrict__ out) {
    const int tid = threadIdx.x;
    const int lane = tid & 63, wave = tid >> 6;
    const int q = lane >> 4;                        // d-chunk: d = q*12 + j
    const int pl = lane & 15;                       // pixel within group
    int pix_g = (blockIdx.x * 4 + wave) * 16 + pl;  // 0..B*HW-1
    int b = pix_g / HW;
    int pix = pix_g - b * HW;
    const float* S0 = S + ((size_t)(b * 3 + 0) * Dd) * HW + pix;
    const float* S1 = S + ((size_t)(b * 3 + 1) * Dd) * HW + pix;
    const float* S2 = S + ((size_t)(b * 3 + 2) * Dd) * HW + pix;
    const int d0 = q * 12;
    float cost[12];
#pragma unroll
    for (int j = 0; j < 12; ++j) {
        int dd = d0 + j;
        float cst = S1[(size_t)dd * HW];
        if (dd > 0)      cst += S0[(size_t)(dd - 1) * HW];
        if (dd < Dd - 1) cst += S2[(size_t)(dd + 1) * HW];
        cost[j] = cst;
    }
    float m = cost[0];
#pragma unroll
    for (int j = 1; j < 12; ++j) m = fmaxf(m, cost[j]);
    m = fmaxf(m, __shfl_xor(m, 16));
    m = fmaxf(m, __shfl_xor(m, 32));
    float sum = 0.f, dep = 0.f, di = 0.f;
#pragma unroll
    for (int j = 0; j < 12; ++j) {
        float e = __expf(cost[j] - m);
        cost[j] = e;
        sum += e;
        dep += e * dvals[b * Dd + d0 + j];
        di  += e * (float)(d0 + j);
    }
    sum += __shfl_xor(sum, 16); sum += __shfl_xor(sum, 32);
    dep += __shfl_xor(dep, 16); dep += __shfl_xor(dep, 32);
    di  += __shfl_xor(di, 16);  di  += __shfl_xor(di, 32);
    float inv = 1.0f / sum;
    di *= inv;
    int didx = (int)di;
    didx = min(max(didx, 0), Dd - 1);
    float win = 0.f;
#pragma unroll
    for (int j = 0; j < 12; ++j) {
        int dd = d0 + j;
        win += ((dd >= didx - 1) && (dd <= didx + 2)) ? cost[j] : 0.f;
    }
    win += __shfl_xor(win, 16); win += __shfl_xor(win, 32);
    if (q == 0) {
        out[pix_g] = dep * inv;
        out[Bb * HW + pix_g] = win * inv;
    }
}

// ---------------- launch ----------------------------------------------------
extern "C" void kernel_launch(void* const* d_in, const int* in_sizes, int n_in,
                              void* d_out, int out_size, void* d_ws, size_t ws_size,
                              hipStream_t stream) {
    const float* features = (const float*)d_in[0];   // (V,B,C,H,W)
    const float* pm       = (const float*)d_in[1];   // (B,V,4,4)
    const float* dvals    = (const float*)d_in[2];   // (B,D)
    const float* reg_w    = (const float*)d_in[4];   // (1,C,3,3,3)
    float* outp = (float*)d_out;

    char* ws = (char*)d_ws;
    ushort* featT = (ushort*)ws;                                 // V*B*H*W*C f16
    size_t featT_bytes = (size_t)Vv * Bb * Hh * Ww * Cc * sizeof(ushort);
    float* P = (float*)(ws + featT_bytes);                       // 48 floats
    float* S = (float*)(ws + featT_bytes + 512);                 // B*3*D*H*W floats
    size_t S_bytes = (size_t)Bb * 3 * Dd * HW * sizeof(float);
    ushort* Bfr = (ushort*)(ws + featT_bytes + 512 + S_bytes);   // 9*64*8 f16

    k_transpose<<<Vv * Bb * Hh, 256, 0, stream>>>(features, pm, reg_w, featT, P, Bfr);
    k_main<<<dim3(80, Dd, Bb), 256, 0, stream>>>(featT, P, dvals, Bfr, S);
    k_post<<<(Bb * HW) / 64, 256, 0, stream>>>(S, dvals, outp);
}

// Round 10
// 151.955 us; speedup vs baseline: 3.9274x; 1.0044x over previous
//
#include <hip/hip_runtime.h>
#include <hip/hip_bf16.h>
#include <hip/hip_fp16.h>

#define Hh 128
#define Ww 160
#define Cc 32
#define Dd 48
#define Bb 2
#define Vv 3
#define HW (Hh*Ww)
#define VS 32    // vsh channel stride in f16 units: no pad; XOR swizzle keeps banks spread

typedef _Float16 f16x8 __attribute__((ext_vector_type(8)));
typedef float f32x4 __attribute__((ext_vector_type(4)));

// ---------------- K1: transpose (v,b,c,h,w) fp32 -> (v,b,h,w,c) fp16 --------
// Block 0 additionally computes proj matrices (threads 0..3) and the f16 MFMA
// B-fragment table Bfr[tap][lane] (threads 0..63): w[kd=lane&15][c=q*8+j][tap].
__global__ void k_transpose(const float* __restrict__ f, const float* __restrict__ pm,
                            const float* __restrict__ wt, ushort* __restrict__ featT,
                            float* __restrict__ P, ushort* __restrict__ Bfr) {
    __shared__ float t[Cc][Ww + 1];
    const int tid = threadIdx.x;
    if (blockIdx.x == 0 && tid < 64) {
        if (tid < Bb * (Vv - 1)) {
            int b = tid >> 1;
            int v = (tid & 1) + 1;
            const float* ref = pm + (b * Vv + 0) * 16;
            const float* src = pm + (b * Vv + v) * 16;
            float A[4][8];
            for (int i = 0; i < 4; ++i)
                for (int j = 0; j < 4; ++j) {
                    A[i][j] = ref[i * 4 + j];
                    A[i][4 + j] = (i == j) ? 1.0f : 0.0f;
                }
            for (int col = 0; col < 4; ++col) {
                int piv = col;
                for (int r = col + 1; r < 4; ++r)
                    if (fabsf(A[r][col]) > fabsf(A[piv][col])) piv = r;
                if (piv != col)
                    for (int j = 0; j < 8; ++j) { float tmp = A[col][j]; A[col][j] = A[piv][j]; A[piv][j] = tmp; }
                float inv = 1.0f / A[col][col];
                for (int j = 0; j < 8; ++j) A[col][j] *= inv;
                for (int r = 0; r < 4; ++r) {
                    if (r == col) continue;
                    float fct = A[r][col];
                    for (int j = 0; j < 8; ++j) A[r][j] -= fct * A[col][j];
                }
            }
            float Pm[3][4];
            for (int i = 0; i < 3; ++i)
                for (int j = 0; j < 4; ++j) {
                    float s = 0.f;
                    for (int k = 0; k < 4; ++k) s += src[i * 4 + k] * A[k][4 + j];
                    Pm[i][j] = s;
                }
            float* o = P + tid * 12;
            o[0] = Pm[0][0]; o[1] = Pm[0][1]; o[2] = Pm[0][2];
            o[3] = Pm[1][0]; o[4] = Pm[1][1]; o[5] = Pm[1][2];
            o[6] = Pm[2][0]; o[7] = Pm[2][1]; o[8] = Pm[2][2];
            o[9] = Pm[0][3]; o[10] = Pm[1][3]; o[11] = Pm[2][3];
        }
        int kd = tid & 15, q = tid >> 4;
        for (int tap = 0; tap < 9; ++tap) {
            ushort* dst = Bfr + (tap * 64 + tid) * 8;
            for (int j = 0; j < 8; ++j) {
                float w = (kd < 3) ? wt[(q * 8 + j) * 27 + kd * 9 + tap] : 0.f;
                __half h = __float2half(w);
                dst[j] = *(ushort*)&h;
            }
        }
    }
    int slice = blockIdx.x;          // vb*H + y
    int vb = slice / Hh, y = slice % Hh;
    const float* src = f + (size_t)vb * Cc * HW + (size_t)y * Ww;
    ushort* dst = featT + ((size_t)vb * Hh + y) * Ww * Cc;
    for (int i = tid; i < Cc * (Ww / 4); i += 256) {
        int c = i / (Ww / 4), x4 = (i - c * (Ww / 4)) * 4;
        float4 v = *(const float4*)(src + (size_t)c * HW + x4);
        t[c][x4] = v.x; t[c][x4 + 1] = v.y; t[c][x4 + 2] = v.z; t[c][x4 + 3] = v.w;
    }
    __syncthreads();
    for (int i = tid; i < Ww * 4; i += 256) {
        int x = i >> 2, c8 = i & 3;
        union { uint4 u; ushort s[8]; } pk;
#pragma unroll
        for (int j = 0; j < 8; ++j) {
            __half h = __float2half(t[c8 * 8 + j][x]);
            pk.s[j] = *(ushort*)&h;
        }
        *(uint4*)&dst[x * Cc + c8 * 8] = pk.u;
    }
}

// ---------------- K2: f16 variance tile + f16 MFMA 3x3 conv -> S ------------
// R6 LDS coord cache + R7 MFMA conv + R8 fp16 + R9 VS=32 swizzle + R10:
// 16-channel stage-B items (648) — one decode/unpack/addr setup serves two
// 8-ch passes (+16B imm offset) — and rofs[] (ref offset precomputed, sentinel
// for OOB) kills the per-item gy/gx recompute. k_main is VALU-issue-bound
// (R9: occupancy +25% -> 0 time delta), so this targets instruction count.
__global__ __launch_bounds__(256, 5)
void k_main(const ushort* __restrict__ featT, const float* __restrict__ P,
            const float* __restrict__ dvals, const ushort* __restrict__ Bfr,
            float* __restrict__ S) {
    __shared__ ushort vsh[324 * VS];          // 20.7 KB f16 variance tile (32 ch)
    __shared__ unsigned int offs[324 * 4];    // 5.2 KB packed corner pixel idx
    __shared__ unsigned int wgts[324 * 4];    // 5.2 KB packed fp16 weights
    __shared__ unsigned int rofs[324];        // 1.3 KB ref offset *Cc, ~0u = OOB
    __shared__ float rt[24];
    const int tid = threadIdx.x;
    const int b = blockIdx.z, d = blockIdx.y;
    const int tileY = blockIdx.x / 10, tileX = blockIdx.x - (blockIdx.x / 10) * 10;

    if (tid < 24) rt[tid] = P[b * 24 + tid];
    const float depth = dvals[b * Dd + d];
    __syncthreads();

    // ---- stage A: bilinear coords for all 324 slots, once per block ----
#pragma unroll 1
    for (int p = tid; p < 324; p += 256) {
        int pyt = p / 18, pxt = p - pyt * 18;
        int gy = tileY * 16 + pyt - 1, gx = tileX * 16 + pxt - 1;
        bool valid = ((unsigned)gy < (unsigned)Hh) && ((unsigned)gx < (unsigned)Ww);
        rofs[p] = valid ? (unsigned)((gy * Ww + gx) * Cc) : 0xFFFFFFFFu;
        if (!valid) continue;
#pragma unroll
        for (int vi = 0; vi < 2; ++vi) {
            const float* M = &rt[vi * 12];
            float fgx = (float)gx, fgy = (float)gy;
            float rx = M[0] * fgx + M[1] * fgy + M[2];
            float ry = M[3] * fgx + M[4] * fgy + M[5];
            float rz = M[6] * fgx + M[7] * fgy + M[8];
            float X = rx * depth + M[9];
            float Y = ry * depth + M[10];
            float Z = rz * depth + M[11];
            float z = (fabsf(Z) < 1e-6f) ? 1e-6f : Z;
            float u = X / z, vv = Y / z;
            float x0f = floorf(u), y0f = floorf(vv);
            float fx = u - x0f, fy = vv - y0f;
            int x0 = (int)x0f, y0 = (int)y0f;
            int x1 = x0 + 1, y1 = y0 + 1;
            bool vx0 = (x0 >= 0) && (x0 <= Ww - 1);
            bool vx1 = (x1 >= 0) && (x1 <= Ww - 1);
            bool vy0 = (y0 >= 0) && (y0 <= Hh - 1);
            bool vy1 = (y1 >= 0) && (y1 <= Hh - 1);
            int xc0 = min(max(x0, 0), Ww - 1), xc1 = min(max(x1, 0), Ww - 1);
            int yc0 = min(max(y0, 0), Hh - 1), yc1 = min(max(y1, 0), Hh - 1);
            unsigned int p00 = (unsigned)(yc0 * Ww + xc0);
            unsigned int p01 = (unsigned)(yc0 * Ww + xc1);
            unsigned int p10 = (unsigned)(yc1 * Ww + xc0);
            unsigned int p11 = (unsigned)(yc1 * Ww + xc1);
            float w0 = (vx0 && vy0) ? (1.f - fx) * (1.f - fy) : 0.f;
            float w1 = (vx1 && vy0) ? fx * (1.f - fy) : 0.f;
            float w2 = (vx0 && vy1) ? (1.f - fx) * fy : 0.f;
            float w3 = (vx1 && vy1) ? fx * fy : 0.f;
            offs[p * 4 + vi * 2 + 0] = p00 | (p01 << 16);
            offs[p * 4 + vi * 2 + 1] = p10 | (p11 << 16);
            __half2 ha = __floats2half2_rn(w0, w1);
            __half2 hb = __floats2half2_rn(w2, w3);
            wgts[p * 4 + vi * 2 + 0] = *(unsigned int*)&ha;
            wgts[p * 4 + vi * 2 + 1] = *(unsigned int*)&hb;
        }
    }
    __syncthreads();

    const ushort* b1 = featT + (size_t)(1 * Bb + b) * HW * Cc;
    const ushort* b2 = featT + (size_t)(2 * Bb + b) * HW * Cc;
    const ushort* br = featT + (size_t)b * HW * Cc;

    // ---- stage B: gather items (slot, c16 0..1): 648 items, f16 math ----
#pragma unroll 1
    for (int i = tid; i < 648; i += 256) {
        int p = i >> 1, half16 = i & 1;
        int c16 = half16 << 4;                 // channel offset 0 or 16
        // dst chunks (logical c8 = half16*2 + h), XOR bank swizzle
        int sw0 = ((half16 * 2 + 0) ^ (p & 3)) * 8;
        int sw1 = ((half16 * 2 + 1) ^ (p & 3)) * 8;
        ushort* dst0 = &vsh[p * VS + sw0];
        ushort* dst1 = &vsh[p * VS + sw1];
        unsigned int ro = rofs[p];
        if (ro == 0xFFFFFFFFu) {
            *(uint4*)dst0 = make_uint4(0u, 0u, 0u, 0u);
            *(uint4*)dst1 = make_uint4(0u, 0u, 0u, 0u);
            continue;
        }
        uint4 oo = *(const uint4*)&offs[p * 4];
        uint4 wwp = *(const uint4*)&wgts[p * 4];
        int o00 = (int)(oo.x & 0xffffu) * Cc + c16;
        int o01 = (int)(oo.x >> 16)     * Cc + c16;
        int o10 = (int)(oo.y & 0xffffu) * Cc + c16;
        int o11 = (int)(oo.y >> 16)     * Cc + c16;
        int o20 = (int)(oo.z & 0xffffu) * Cc + c16;
        int o21 = (int)(oo.z >> 16)     * Cc + c16;
        int o30 = (int)(oo.w & 0xffffu) * Cc + c16;
        int o31 = (int)(oo.w >> 16)     * Cc + c16;
        int orf = (int)ro + c16;
        __half2 hv0 = *(__half2*)&wwp.x;   // v0: (w0,w1)
        __half2 hv1 = *(__half2*)&wwp.y;   // v0: (w2,w3)
        __half2 hv2 = *(__half2*)&wwp.z;   // v1: (w0,w1)
        __half2 hv3 = *(__half2*)&wwp.w;   // v1: (w2,w3)
        __half2 w00 = __half2half2(__low2half(hv0)), w01 = __half2half2(__high2half(hv0));
        __half2 w02 = __half2half2(__low2half(hv1)), w03 = __half2half2(__high2half(hv1));
        __half2 w10 = __half2half2(__low2half(hv2)), w11 = __half2half2(__high2half(hv2));
        __half2 w12 = __half2half2(__low2half(hv3)), w13 = __half2half2(__high2half(hv3));
        const __half2 third2 = __float2half2_rn(1.0f / 3.0f);
        union U { uint4 u; __half2 h[4]; };
#pragma unroll
        for (int h = 0; h < 2; ++h) {
            int e = h * 8;
            U R, C0, C1, C2, C3, E0, E1, E2, E3, V;
            R.u  = *(const uint4*)(br + orf + e);
            C0.u = *(const uint4*)(b1 + o00 + e);
            C1.u = *(const uint4*)(b1 + o01 + e);
            C2.u = *(const uint4*)(b1 + o10 + e);
            C3.u = *(const uint4*)(b1 + o11 + e);
            E0.u = *(const uint4*)(b2 + o20 + e);
            E1.u = *(const uint4*)(b2 + o21 + e);
            E2.u = *(const uint4*)(b2 + o30 + e);
            E3.u = *(const uint4*)(b2 + o31 + e);
#pragma unroll
            for (int k = 0; k < 4; ++k) {
                __half2 s1 = __hmul2(w00, C0.h[k]);
                s1 = __hfma2(w01, C1.h[k], s1);
                s1 = __hfma2(w02, C2.h[k], s1);
                s1 = __hfma2(w03, C3.h[k], s1);
                __half2 s2 = __hmul2(w10, E0.h[k]);
                s2 = __hfma2(w11, E1.h[k], s2);
                s2 = __hfma2(w12, E2.h[k], s2);
                s2 = __hfma2(w13, E3.h[k], s2);
                __half2 r = R.h[k];
                __half2 sum = __hadd2(__hadd2(r, s1), s2);
                __half2 sq = __hmul2(r, r);
                sq = __hfma2(s1, s1, sq);
                sq = __hfma2(s2, s2, sq);
                __half2 m = __hmul2(sum, third2);
                __half2 var = __hfma2(__hneg2(m), m, __hmul2(sq, third2));
                V.h[k] = var;
            }
            *(uint4*)(h ? dst1 : dst0) = V.u;
        }
    }
    __syncthreads();

    // ---- phase 2: f16 MFMA conv. Wave covers 4 row-groups of 16 pixels. ----
    const int lane = tid & 63;
    const int wave = tid >> 6;
    const int q = lane >> 4;      // k-chunk selector (channels q*8..+7) / D row quad
    const int n = lane & 15;      // A: pixel-x ; B/D: kd column
    uint4 bf[9];
#pragma unroll
    for (int tap = 0; tap < 9; ++tap)
        bf[tap] = *(const uint4*)(Bfr + ((tap * 64 + lane) << 3));
#pragma unroll 1
    for (int rr = 0; rr < 4; ++rr) {
        int row = wave * 4 + rr;            // ty of this 16-pixel row-group
        f32x4 acc = {0.f, 0.f, 0.f, 0.f};
#pragma unroll
        for (int tap = 0; tap < 9; ++tap) {
            int kh = tap / 3, kw = tap - 3 * (tap / 3);
            int slot = (row + kh) * 18 + n + kw;
            union { uint4 u; f16x8 v; } A, Bf;
            A.u  = *(const uint4*)&vsh[slot * VS + (q ^ (slot & 3)) * 8];
            Bf.u = bf[tap];
            acc = __builtin_amdgcn_mfma_f32_16x16x32_f16(A.v, Bf.v, acc, 0, 0, 0);
        }
        if (n < 3) {   // lane holds D[pixel-x = q*4+reg][kd = n]
            int gy = tileY * 16 + row;
            int gxb = tileX * 16 + q * 4;
            float4 o = make_float4(acc[0], acc[1], acc[2], acc[3]);
            *(float4*)&S[((size_t)(b * 3 + n) * Dd + d) * HW + (size_t)gy * Ww + gxb] = o;
        }
    }
}

// ---------------- K3: cost, softmax, depth + conf; 4 lanes-of-depth/pixel ---
__global__ __launch_bounds__(256)
void k_post(const float* __restrict__ S, const float* __restrict__ dvals,
            float* __restrict__ out) {
    const int tid = threadIdx.x;
    const int lane = tid & 63, wave = tid >> 6;
    const int q = lane >> 4;                        // d-chunk: d = q*12 + j
    const int pl = lane & 15;                       // pixel within group
    int pix_g = (blockIdx.x * 4 + wave) * 16 + pl;  // 0..B*HW-1
    int b = pix_g / HW;
    int pix = pix_g - b * HW;
    const float* S0 = S + ((size_t)(b * 3 + 0) * Dd) * HW + pix;
    const float* S1 = S + ((size_t)(b * 3 + 1) * Dd) * HW + pix;
    const float* S2 = S + ((size_t)(b * 3 + 2) * Dd) * HW + pix;
    const int d0 = q * 12;
    float cost[12];
#pragma unroll
    for (int j = 0; j < 12; ++j) {
        int dd = d0 + j;
        float cst = S1[(size_t)dd * HW];
        if (dd > 0)      cst += S0[(size_t)(dd - 1) * HW];
        if (dd < Dd - 1) cst += S2[(size_t)(dd + 1) * HW];
        cost[j] = cst;
    }
    float m = cost[0];
#pragma unroll
    for (int j = 1; j < 12; ++j) m = fmaxf(m, cost[j]);
    m = fmaxf(m, __shfl_xor(m, 16));
    m = fmaxf(m, __shfl_xor(m, 32));
    float sum = 0.f, dep = 0.f, di = 0.f;
#pragma unroll
    for (int j = 0; j < 12; ++j) {
        float e = __expf(cost[j] - m);
        cost[j] = e;
        sum += e;
        dep += e * dvals[b * Dd + d0 + j];
        di  += e * (float)(d0 + j);
    }
    sum += __shfl_xor(sum, 16); sum += __shfl_xor(sum, 32);
    dep += __shfl_xor(dep, 16); dep += __shfl_xor(dep, 32);
    di  += __shfl_xor(di, 16);  di  += __shfl_xor(di, 32);
    float inv = 1.0f / sum;
    di *= inv;
    int didx = (int)di;
    didx = min(max(didx, 0), Dd - 1);
    float win = 0.f;
#pragma unroll
    for (int j = 0; j < 12; ++j) {
        int dd = d0 + j;
        win += ((dd >= didx - 1) && (dd <= didx + 2)) ? cost[j] : 0.f;
    }
    win += __shfl_xor(win, 16); win += __shfl_xor(win, 32);
    if (q == 0) {
        out[pix_g] = dep * inv;
        out[Bb * HW + pix_g] = win * inv;
    }
}

// ---------------- launch ----------------------------------------------------
extern "C" void kernel_launch(void* const* d_in, const int* in_sizes, int n_in,
                              void* d_out, int out_size, void* d_ws, size_t ws_size,
                              hipStream_t stream) {
    const float* features = (const float*)d_in[0];   // (V,B,C,H,W)
    const float* pm       = (const float*)d_in[1];   // (B,V,4,4)
    const float* dvals    = (const float*)d_in[2];   // (B,D)
    const float* reg_w    = (const float*)d_in[4];   // (1,C,3,3,3)
    float* outp = (float*)d_out;

    char* ws = (char*)d_ws;
    ushort* featT = (ushort*)ws;                                 // V*B*H*W*C f16
    size_t featT_bytes = (size_t)Vv * Bb * Hh * Ww * Cc * sizeof(ushort);
    float* P = (float*)(ws + featT_bytes);                       // 48 floats
    float* S = (float*)(ws + featT_bytes + 512);                 // B*3*D*H*W floats
    size_t S_bytes = (size_t)Bb * 3 * Dd * HW * sizeof(float);
    ushort* Bfr = (ushort*)(ws + featT_bytes + 512 + S_bytes);   // 9*64*8 f16

    k_transpose<<<Vv * Bb * Hh, 256, 0, stream>>>(features, pm, reg_w, featT, P, Bfr);
    k_main<<<dim3(80, Dd, Bb), 256, 0, stream>>>(featT, P, dvals, Bfr, S);
    k_post<<<(Bb * HW) / 64, 256, 0, stream>>>(S, dvals, outp);
}

// Round 11
// 150.589 us; speedup vs baseline: 3.9630x; 1.0091x over previous
//
#include <hip/hip_runtime.h>
#include <hip/hip_bf16.h>
#include <hip/hip_fp16.h>

#define Hh 128
#define Ww 160
#define Cc 32
#define Dd 48
#define Bb 2
#define Vv 3
#define HW (Hh*Ww)
#define VS 32    // vsh channel stride in f16 units: no pad; XOR swizzle keeps banks spread

typedef _Float16 f16x8 __attribute__((ext_vector_type(8)));
typedef float f32x4 __attribute__((ext_vector_type(4)));

// ---------------- K1: transpose (v,b,c,h,w) fp32 -> (v,b,h,w,c) fp16 --------
// Block 0 additionally computes proj matrices (threads 0..3) and the f16 MFMA
// B-fragment table Bfr[tap][lane] (threads 0..63): w[kd=lane&15][c=q*8+j][tap].
__global__ void k_transpose(const float* __restrict__ f, const float* __restrict__ pm,
                            const float* __restrict__ wt, ushort* __restrict__ featT,
                            float* __restrict__ P, ushort* __restrict__ Bfr) {
    __shared__ float t[Cc][Ww + 1];
    const int tid = threadIdx.x;
    if (blockIdx.x == 0 && tid < 64) {
        if (tid < Bb * (Vv - 1)) {
            int b = tid >> 1;
            int v = (tid & 1) + 1;
            const float* ref = pm + (b * Vv + 0) * 16;
            const float* src = pm + (b * Vv + v) * 16;
            float A[4][8];
            for (int i = 0; i < 4; ++i)
                for (int j = 0; j < 4; ++j) {
                    A[i][j] = ref[i * 4 + j];
                    A[i][4 + j] = (i == j) ? 1.0f : 0.0f;
                }
            for (int col = 0; col < 4; ++col) {
                int piv = col;
                for (int r = col + 1; r < 4; ++r)
                    if (fabsf(A[r][col]) > fabsf(A[piv][col])) piv = r;
                if (piv != col)
                    for (int j = 0; j < 8; ++j) { float tmp = A[col][j]; A[col][j] = A[piv][j]; A[piv][j] = tmp; }
                float inv = 1.0f / A[col][col];
                for (int j = 0; j < 8; ++j) A[col][j] *= inv;
                for (int r = 0; r < 4; ++r) {
                    if (r == col) continue;
                    float fct = A[r][col];
                    for (int j = 0; j < 8; ++j) A[r][j] -= fct * A[col][j];
                }
            }
            float Pm[3][4];
            for (int i = 0; i < 3; ++i)
                for (int j = 0; j < 4; ++j) {
                    float s = 0.f;
                    for (int k = 0; k < 4; ++k) s += src[i * 4 + k] * A[k][4 + j];
                    Pm[i][j] = s;
                }
            float* o = P + tid * 12;
            o[0] = Pm[0][0]; o[1] = Pm[0][1]; o[2] = Pm[0][2];
            o[3] = Pm[1][0]; o[4] = Pm[1][1]; o[5] = Pm[1][2];
            o[6] = Pm[2][0]; o[7] = Pm[2][1]; o[8] = Pm[2][2];
            o[9] = Pm[0][3]; o[10] = Pm[1][3]; o[11] = Pm[2][3];
        }
        int kd = tid & 15, q = tid >> 4;
        for (int tap = 0; tap < 9; ++tap) {
            ushort* dst = Bfr + (tap * 64 + tid) * 8;
            for (int j = 0; j < 8; ++j) {
                float w = (kd < 3) ? wt[(q * 8 + j) * 27 + kd * 9 + tap] : 0.f;
                __half h = __float2half(w);
                dst[j] = *(ushort*)&h;
            }
        }
    }
    int slice = blockIdx.x;          // vb*H + y
    int vb = slice / Hh, y = slice % Hh;
    const float* src = f + (size_t)vb * Cc * HW + (size_t)y * Ww;
    ushort* dst = featT + ((size_t)vb * Hh + y) * Ww * Cc;
    for (int i = tid; i < Cc * (Ww / 4); i += 256) {
        int c = i / (Ww / 4), x4 = (i - c * (Ww / 4)) * 4;
        float4 v = *(const float4*)(src + (size_t)c * HW + x4);
        t[c][x4] = v.x; t[c][x4 + 1] = v.y; t[c][x4 + 2] = v.z; t[c][x4 + 3] = v.w;
    }
    __syncthreads();
    for (int i = tid; i < Ww * 4; i += 256) {
        int x = i >> 2, c8 = i & 3;
        union { uint4 u; ushort s[8]; } pk;
#pragma unroll
        for (int j = 0; j < 8; ++j) {
            __half h = __float2half(t[c8 * 8 + j][x]);
            pk.s[j] = *(ushort*)&h;
        }
        *(uint4*)&dst[x * Cc + c8 * 8] = pk.u;
    }
}

// ---------------- K2: f16 variance tile + f16 MFMA 3x3 conv -> S (f16) ------
// R11: R10's 16-ch stage-B items (fewer VALU) at R9's occupancy — rofs dropped
// (validity recomputed inline, ~6 VALU) so LDS = 31.2 KB -> 5 blocks/CU
// (R10's 32.8 KB fell to 4 blocks after runtime-reserved LDS). S stored f16:
// halves k_main WRITE and k_post FETCH.
__global__ __launch_bounds__(256, 5)
void k_main(const ushort* __restrict__ featT, const float* __restrict__ P,
            const float* __restrict__ dvals, const ushort* __restrict__ Bfr,
            ushort* __restrict__ S) {
    __shared__ ushort vsh[324 * VS];          // 20.7 KB f16 variance tile (32 ch)
    __shared__ unsigned int offs[324 * 4];    // 5.2 KB packed corner pixel idx
    __shared__ unsigned int wgts[324 * 4];    // 5.2 KB packed fp16 weights
    __shared__ float rt[24];
    const int tid = threadIdx.x;
    const int b = blockIdx.z, d = blockIdx.y;
    const int tileY = blockIdx.x / 10, tileX = blockIdx.x - (blockIdx.x / 10) * 10;

    if (tid < 24) rt[tid] = P[b * 24 + tid];
    const float depth = dvals[b * Dd + d];
    __syncthreads();

    // ---- stage A: bilinear coords for all 324 slots, once per block ----
#pragma unroll 1
    for (int p = tid; p < 324; p += 256) {
        int pyt = p / 18, pxt = p - pyt * 18;
        int gy = tileY * 16 + pyt - 1, gx = tileX * 16 + pxt - 1;
        if ((unsigned)gy >= (unsigned)Hh || (unsigned)gx >= (unsigned)Ww) continue;
#pragma unroll
        for (int vi = 0; vi < 2; ++vi) {
            const float* M = &rt[vi * 12];
            float fgx = (float)gx, fgy = (float)gy;
            float rx = M[0] * fgx + M[1] * fgy + M[2];
            float ry = M[3] * fgx + M[4] * fgy + M[5];
            float rz = M[6] * fgx + M[7] * fgy + M[8];
            float X = rx * depth + M[9];
            float Y = ry * depth + M[10];
            float Z = rz * depth + M[11];
            float z = (fabsf(Z) < 1e-6f) ? 1e-6f : Z;
            float u = X / z, vv = Y / z;
            float x0f = floorf(u), y0f = floorf(vv);
            float fx = u - x0f, fy = vv - y0f;
            int x0 = (int)x0f, y0 = (int)y0f;
            int x1 = x0 + 1, y1 = y0 + 1;
            bool vx0 = (x0 >= 0) && (x0 <= Ww - 1);
            bool vx1 = (x1 >= 0) && (x1 <= Ww - 1);
            bool vy0 = (y0 >= 0) && (y0 <= Hh - 1);
            bool vy1 = (y1 >= 0) && (y1 <= Hh - 1);
            int xc0 = min(max(x0, 0), Ww - 1), xc1 = min(max(x1, 0), Ww - 1);
            int yc0 = min(max(y0, 0), Hh - 1), yc1 = min(max(y1, 0), Hh - 1);
            unsigned int p00 = (unsigned)(yc0 * Ww + xc0);
            unsigned int p01 = (unsigned)(yc0 * Ww + xc1);
            unsigned int p10 = (unsigned)(yc1 * Ww + xc0);
            unsigned int p11 = (unsigned)(yc1 * Ww + xc1);
            float w0 = (vx0 && vy0) ? (1.f - fx) * (1.f - fy) : 0.f;
            float w1 = (vx1 && vy0) ? fx * (1.f - fy) : 0.f;
            float w2 = (vx0 && vy1) ? (1.f - fx) * fy : 0.f;
            float w3 = (vx1 && vy1) ? fx * fy : 0.f;
            offs[p * 4 + vi * 2 + 0] = p00 | (p01 << 16);
            offs[p * 4 + vi * 2 + 1] = p10 | (p11 << 16);
            __half2 ha = __floats2half2_rn(w0, w1);
            __half2 hb = __floats2half2_rn(w2, w3);
            wgts[p * 4 + vi * 2 + 0] = *(unsigned int*)&ha;
            wgts[p * 4 + vi * 2 + 1] = *(unsigned int*)&hb;
        }
    }
    __syncthreads();

    const ushort* b1 = featT + (size_t)(1 * Bb + b) * HW * Cc;
    const ushort* b2 = featT + (size_t)(2 * Bb + b) * HW * Cc;
    const ushort* br = featT + (size_t)b * HW * Cc;

    // ---- stage B: gather items (slot, c16 0..1): 648 items, f16 math ----
#pragma unroll 1
    for (int i = tid; i < 648; i += 256) {
        int p = i >> 1, half16 = i & 1;
        int c16 = half16 << 4;                 // channel offset 0 or 16
        int pyt = p / 18, pxt = p - pyt * 18;
        int gy = tileY * 16 + pyt - 1, gx = tileX * 16 + pxt - 1;
        int sw0 = ((half16 * 2 + 0) ^ (p & 3)) * 8;
        int sw1 = ((half16 * 2 + 1) ^ (p & 3)) * 8;
        ushort* dst0 = &vsh[p * VS + sw0];
        ushort* dst1 = &vsh[p * VS + sw1];
        if ((unsigned)gy >= (unsigned)Hh || (unsigned)gx >= (unsigned)Ww) {
            *(uint4*)dst0 = make_uint4(0u, 0u, 0u, 0u);
            *(uint4*)dst1 = make_uint4(0u, 0u, 0u, 0u);
            continue;
        }
        uint4 oo = *(const uint4*)&offs[p * 4];
        uint4 wwp = *(const uint4*)&wgts[p * 4];
        int o00 = (int)(oo.x & 0xffffu) * Cc + c16;
        int o01 = (int)(oo.x >> 16)     * Cc + c16;
        int o10 = (int)(oo.y & 0xffffu) * Cc + c16;
        int o11 = (int)(oo.y >> 16)     * Cc + c16;
        int o20 = (int)(oo.z & 0xffffu) * Cc + c16;
        int o21 = (int)(oo.z >> 16)     * Cc + c16;
        int o30 = (int)(oo.w & 0xffffu) * Cc + c16;
        int o31 = (int)(oo.w >> 16)     * Cc + c16;
        int orf = (gy * Ww + gx) * Cc + c16;
        __half2 hv0 = *(__half2*)&wwp.x;   // v0: (w0,w1)
        __half2 hv1 = *(__half2*)&wwp.y;   // v0: (w2,w3)
        __half2 hv2 = *(__half2*)&wwp.z;   // v1: (w0,w1)
        __half2 hv3 = *(__half2*)&wwp.w;   // v1: (w2,w3)
        __half2 w00 = __half2half2(__low2half(hv0)), w01 = __half2half2(__high2half(hv0));
        __half2 w02 = __half2half2(__low2half(hv1)), w03 = __half2half2(__high2half(hv1));
        __half2 w10 = __half2half2(__low2half(hv2)), w11 = __half2half2(__high2half(hv2));
        __half2 w12 = __half2half2(__low2half(hv3)), w13 = __half2half2(__high2half(hv3));
        const __half2 third2 = __float2half2_rn(1.0f / 3.0f);
        union U { uint4 u; __half2 h[4]; };
#pragma unroll
        for (int h = 0; h < 2; ++h) {
            int e = h * 8;
            U R, C0, C1, C2, C3, E0, E1, E2, E3, V;
            R.u  = *(const uint4*)(br + orf + e);
            C0.u = *(const uint4*)(b1 + o00 + e);
            C1.u = *(const uint4*)(b1 + o01 + e);
            C2.u = *(const uint4*)(b1 + o10 + e);
            C3.u = *(const uint4*)(b1 + o11 + e);
            E0.u = *(const uint4*)(b2 + o20 + e);
            E1.u = *(const uint4*)(b2 + o21 + e);
            E2.u = *(const uint4*)(b2 + o30 + e);
            E3.u = *(const uint4*)(b2 + o31 + e);
#pragma unroll
            for (int k = 0; k < 4; ++k) {
                __half2 s1 = __hmul2(w00, C0.h[k]);
                s1 = __hfma2(w01, C1.h[k], s1);
                s1 = __hfma2(w02, C2.h[k], s1);
                s1 = __hfma2(w03, C3.h[k], s1);
                __half2 s2 = __hmul2(w10, E0.h[k]);
                s2 = __hfma2(w11, E1.h[k], s2);
                s2 = __hfma2(w12, E2.h[k], s2);
                s2 = __hfma2(w13, E3.h[k], s2);
                __half2 r = R.h[k];
                __half2 sum = __hadd2(__hadd2(r, s1), s2);
                __half2 sq = __hmul2(r, r);
                sq = __hfma2(s1, s1, sq);
                sq = __hfma2(s2, s2, sq);
                __half2 m = __hmul2(sum, third2);
                __half2 var = __hfma2(__hneg2(m), m, __hmul2(sq, third2));
                V.h[k] = var;
            }
            *(uint4*)(h ? dst1 : dst0) = V.u;
        }
    }
    __syncthreads();

    // ---- phase 2: f16 MFMA conv. Wave covers 4 row-groups of 16 pixels. ----
    const int lane = tid & 63;
    const int wave = tid >> 6;
    const int q = lane >> 4;      // k-chunk selector (channels q*8..+7) / D row quad
    const int n = lane & 15;      // A: pixel-x ; B/D: kd column
    uint4 bf[9];
#pragma unroll
    for (int tap = 0; tap < 9; ++tap)
        bf[tap] = *(const uint4*)(Bfr + ((tap * 64 + lane) << 3));
#pragma unroll 1
    for (int rr = 0; rr < 4; ++rr) {
        int row = wave * 4 + rr;            // ty of this 16-pixel row-group
        f32x4 acc = {0.f, 0.f, 0.f, 0.f};
#pragma unroll
        for (int tap = 0; tap < 9; ++tap) {
            int kh = tap / 3, kw = tap - 3 * (tap / 3);
            int slot = (row + kh) * 18 + n + kw;
            union { uint4 u; f16x8 v; } A, Bf;
            A.u  = *(const uint4*)&vsh[slot * VS + (q ^ (slot & 3)) * 8];
            Bf.u = bf[tap];
            acc = __builtin_amdgcn_mfma_f32_16x16x32_f16(A.v, Bf.v, acc, 0, 0, 0);
        }
        if (n < 3) {   // lane holds D[pixel-x = q*4+reg][kd = n]; store 4 px as f16
            int gy = tileY * 16 + row;
            int gxb = tileX * 16 + q * 4;
            union { uint2 u; ushort s[4]; } pk;
#pragma unroll
            for (int j = 0; j < 4; ++j) {
                __half h = __float2half(acc[j]);
                pk.s[j] = *(ushort*)&h;
            }
            *(uint2*)&S[((size_t)(b * 3 + n) * Dd + d) * HW + (size_t)gy * Ww + gxb] = pk.u;
        }
    }
}

// ---------------- K3: cost, softmax, depth + conf; 4 lanes-of-depth/pixel ---
__global__ __launch_bounds__(256)
void k_post(const ushort* __restrict__ S, const float* __restrict__ dvals,
            float* __restrict__ out) {
    const int tid = threadIdx.x;
    const int lane = tid & 63, wave = tid >> 6;
    const int q = lane >> 4;                        // d-chunk: d = q*12 + j
    const int pl = lane & 15;                       // pixel within group
    int pix_g = (blockIdx.x * 4 + wave) * 16 + pl;  // 0..B*HW-1
    int b = pix_g / HW;
    int pix = pix_g - b * HW;
    const ushort* S0 = S + ((size_t)(b * 3 + 0) * Dd) * HW + pix;
    const ushort* S1 = S + ((size_t)(b * 3 + 1) * Dd) * HW + pix;
    const ushort* S2 = S + ((size_t)(b * 3 + 2) * Dd) * HW + pix;
    const int d0 = q * 12;
    float cost[12];
#pragma unroll
    for (int j = 0; j < 12; ++j) {
        int dd = d0 + j;
        float cst = __half2float(*(const __half*)&S1[(size_t)dd * HW]);
        if (dd > 0)      cst += __half2float(*(const __half*)&S0[(size_t)(dd - 1) * HW]);
        if (dd < Dd - 1) cst += __half2float(*(const __half*)&S2[(size_t)(dd + 1) * HW]);
        cost[j] = cst;
    }
    float m = cost[0];
#pragma unroll
    for (int j = 1; j < 12; ++j) m = fmaxf(m, cost[j]);
    m = fmaxf(m, __shfl_xor(m, 16));
    m = fmaxf(m, __shfl_xor(m, 32));
    float sum = 0.f, dep = 0.f, di = 0.f;
#pragma unroll
    for (int j = 0; j < 12; ++j) {
        float e = __expf(cost[j] - m);
        cost[j] = e;
        sum += e;
        dep += e * dvals[b * Dd + d0 + j];
        di  += e * (float)(d0 + j);
    }
    sum += __shfl_xor(sum, 16); sum += __shfl_xor(sum, 32);
    dep += __shfl_xor(dep, 16); dep += __shfl_xor(dep, 32);
    di  += __shfl_xor(di, 16);  di  += __shfl_xor(di, 32);
    float inv = 1.0f / sum;
    di *= inv;
    int didx = (int)di;
    didx = min(max(didx, 0), Dd - 1);
    float win = 0.f;
#pragma unroll
    for (int j = 0; j < 12; ++j) {
        int dd = d0 + j;
        win += ((dd >= didx - 1) && (dd <= didx + 2)) ? cost[j] : 0.f;
    }
    win += __shfl_xor(win, 16); win += __shfl_xor(win, 32);
    if (q == 0) {
        out[pix_g] = dep * inv;
        out[Bb * HW + pix_g] = win * inv;
    }
}

// ---------------- launch ----------------------------------------------------
extern "C" void kernel_launch(void* const* d_in, const int* in_sizes, int n_in,
                              void* d_out, int out_size, void* d_ws, size_t ws_size,
                              hipStream_t stream) {
    const float* features = (const float*)d_in[0];   // (V,B,C,H,W)
    const float* pm       = (const float*)d_in[1];   // (B,V,4,4)
    const float* dvals    = (const float*)d_in[2];   // (B,D)
    const float* reg_w    = (const float*)d_in[4];   // (1,C,3,3,3)
    float* outp = (float*)d_out;

    char* ws = (char*)d_ws;
    ushort* featT = (ushort*)ws;                                 // V*B*H*W*C f16
    size_t featT_bytes = (size_t)Vv * Bb * Hh * Ww * Cc * sizeof(ushort);
    float* P = (float*)(ws + featT_bytes);                       // 48 floats
    ushort* S = (ushort*)(ws + featT_bytes + 512);               // B*3*D*H*W f16
    size_t S_bytes = (size_t)Bb * 3 * Dd * HW * sizeof(ushort);
    ushort* Bfr = (ushort*)(ws + featT_bytes + 512 + S_bytes);   // 9*64*8 f16

    k_transpose<<<Vv * Bb * Hh, 256, 0, stream>>>(features, pm, reg_w, featT, P, Bfr);
    k_main<<<dim3(80, Dd, Bb), 256, 0, stream>>>(featT, P, dvals, Bfr, S);
    k_post<<<(Bb * HW) / 64, 256, 0, stream>>>(S, dvals, outp);
}

// Round 12
// 149.550 us; speedup vs baseline: 3.9905x; 1.0069x over previous
//
#include <hip/hip_runtime.h>
#include <hip/hip_bf16.h>
#include <hip/hip_fp16.h>

#define Hh 128
#define Ww 160
#define Cc 32
#define Dd 48
#define Bb 2
#define Vv 3
#define HW (Hh*Ww)
#define VS 32    // vsh channel stride in f16 units: no pad; XOR swizzle keeps banks spread

typedef _Float16 f16x8 __attribute__((ext_vector_type(8)));
typedef float f32x4 __attribute__((ext_vector_type(4)));

// ---------------- K1: transpose (v,b,c,h,w) fp32 -> (v,b,h,w,c) fp16 --------
// Block 0 additionally computes proj matrices (threads 0..3) and the f16 MFMA
// B-fragment table Bfr[tap][lane] (threads 0..63): w[kd=lane&15][c=q*8+j][tap].
__global__ void k_transpose(const float* __restrict__ f, const float* __restrict__ pm,
                            const float* __restrict__ wt, ushort* __restrict__ featT,
                            float* __restrict__ P, ushort* __restrict__ Bfr) {
    __shared__ float t[Cc][Ww + 1];
    const int tid = threadIdx.x;
    if (blockIdx.x == 0 && tid < 64) {
        if (tid < Bb * (Vv - 1)) {
            int b = tid >> 1;
            int v = (tid & 1) + 1;
            const float* ref = pm + (b * Vv + 0) * 16;
            const float* src = pm + (b * Vv + v) * 16;
            float A[4][8];
            for (int i = 0; i < 4; ++i)
                for (int j = 0; j < 4; ++j) {
                    A[i][j] = ref[i * 4 + j];
                    A[i][4 + j] = (i == j) ? 1.0f : 0.0f;
                }
            for (int col = 0; col < 4; ++col) {
                int piv = col;
                for (int r = col + 1; r < 4; ++r)
                    if (fabsf(A[r][col]) > fabsf(A[piv][col])) piv = r;
                if (piv != col)
                    for (int j = 0; j < 8; ++j) { float tmp = A[col][j]; A[col][j] = A[piv][j]; A[piv][j] = tmp; }
                float inv = 1.0f / A[col][col];
                for (int j = 0; j < 8; ++j) A[col][j] *= inv;
                for (int r = 0; r < 4; ++r) {
                    if (r == col) continue;
                    float fct = A[r][col];
                    for (int j = 0; j < 8; ++j) A[r][j] -= fct * A[col][j];
                }
            }
            float Pm[3][4];
            for (int i = 0; i < 3; ++i)
                for (int j = 0; j < 4; ++j) {
                    float s = 0.f;
                    for (int k = 0; k < 4; ++k) s += src[i * 4 + k] * A[k][4 + j];
                    Pm[i][j] = s;
                }
            float* o = P + tid * 12;
            o[0] = Pm[0][0]; o[1] = Pm[0][1]; o[2] = Pm[0][2];
            o[3] = Pm[1][0]; o[4] = Pm[1][1]; o[5] = Pm[1][2];
            o[6] = Pm[2][0]; o[7] = Pm[2][1]; o[8] = Pm[2][2];
            o[9] = Pm[0][3]; o[10] = Pm[1][3]; o[11] = Pm[2][3];
        }
        int kd = tid & 15, q = tid >> 4;
        for (int tap = 0; tap < 9; ++tap) {
            ushort* dst = Bfr + (tap * 64 + tid) * 8;
            for (int j = 0; j < 8; ++j) {
                float w = (kd < 3) ? wt[(q * 8 + j) * 27 + kd * 9 + tap] : 0.f;
                __half h = __float2half(w);
                dst[j] = *(ushort*)&h;
            }
        }
    }
    int slice = blockIdx.x;          // vb*H + y
    int vb = slice / Hh, y = slice % Hh;
    const float* src = f + (size_t)vb * Cc * HW + (size_t)y * Ww;
    ushort* dst = featT + ((size_t)vb * Hh + y) * Ww * Cc;
    for (int i = tid; i < Cc * (Ww / 4); i += 256) {
        int c = i / (Ww / 4), x4 = (i - c * (Ww / 4)) * 4;
        float4 v = *(const float4*)(src + (size_t)c * HW + x4);
        t[c][x4] = v.x; t[c][x4 + 1] = v.y; t[c][x4 + 2] = v.z; t[c][x4 + 3] = v.w;
    }
    __syncthreads();
    for (int i = tid; i < Ww * 4; i += 256) {
        int x = i >> 2, c8 = i & 3;
        union { uint4 u; ushort s[8]; } pk;
#pragma unroll
        for (int j = 0; j < 8; ++j) {
            __half h = __float2half(t[c8 * 8 + j][x]);
            pk.s[j] = *(ushort*)&h;
        }
        *(uint4*)&dst[x * Cc + c8 * 8] = pk.u;
    }
}

// ---------------- K2: f16 variance tile + f16 MFMA 3x3 conv -> S (f16) ------
// (unchanged from R11 — k_main sits at a ~77 us structural floor: occupancy
// +25% (R9) and instructions -20% (R10/R11) both left time unchanged.)
__global__ __launch_bounds__(256, 5)
void k_main(const ushort* __restrict__ featT, const float* __restrict__ P,
            const float* __restrict__ dvals, const ushort* __restrict__ Bfr,
            ushort* __restrict__ S) {
    __shared__ ushort vsh[324 * VS];          // 20.7 KB f16 variance tile (32 ch)
    __shared__ unsigned int offs[324 * 4];    // 5.2 KB packed corner pixel idx
    __shared__ unsigned int wgts[324 * 4];    // 5.2 KB packed fp16 weights
    __shared__ float rt[24];
    const int tid = threadIdx.x;
    const int b = blockIdx.z, d = blockIdx.y;
    const int tileY = blockIdx.x / 10, tileX = blockIdx.x - (blockIdx.x / 10) * 10;

    if (tid < 24) rt[tid] = P[b * 24 + tid];
    const float depth = dvals[b * Dd + d];
    __syncthreads();

    // ---- stage A: bilinear coords for all 324 slots, once per block ----
#pragma unroll 1
    for (int p = tid; p < 324; p += 256) {
        int pyt = p / 18, pxt = p - pyt * 18;
        int gy = tileY * 16 + pyt - 1, gx = tileX * 16 + pxt - 1;
        if ((unsigned)gy >= (unsigned)Hh || (unsigned)gx >= (unsigned)Ww) continue;
#pragma unroll
        for (int vi = 0; vi < 2; ++vi) {
            const float* M = &rt[vi * 12];
            float fgx = (float)gx, fgy = (float)gy;
            float rx = M[0] * fgx + M[1] * fgy + M[2];
            float ry = M[3] * fgx + M[4] * fgy + M[5];
            float rz = M[6] * fgx + M[7] * fgy + M[8];
            float X = rx * depth + M[9];
            float Y = ry * depth + M[10];
            float Z = rz * depth + M[11];
            float z = (fabsf(Z) < 1e-6f) ? 1e-6f : Z;
            float u = X / z, vv = Y / z;
            float x0f = floorf(u), y0f = floorf(vv);
            float fx = u - x0f, fy = vv - y0f;
            int x0 = (int)x0f, y0 = (int)y0f;
            int x1 = x0 + 1, y1 = y0 + 1;
            bool vx0 = (x0 >= 0) && (x0 <= Ww - 1);
            bool vx1 = (x1 >= 0) && (x1 <= Ww - 1);
            bool vy0 = (y0 >= 0) && (y0 <= Hh - 1);
            bool vy1 = (y1 >= 0) && (y1 <= Hh - 1);
            int xc0 = min(max(x0, 0), Ww - 1), xc1 = min(max(x1, 0), Ww - 1);
            int yc0 = min(max(y0, 0), Hh - 1), yc1 = min(max(y1, 0), Hh - 1);
            unsigned int p00 = (unsigned)(yc0 * Ww + xc0);
            unsigned int p01 = (unsigned)(yc0 * Ww + xc1);
            unsigned int p10 = (unsigned)(yc1 * Ww + xc0);
            unsigned int p11 = (unsigned)(yc1 * Ww + xc1);
            float w0 = (vx0 && vy0) ? (1.f - fx) * (1.f - fy) : 0.f;
            float w1 = (vx1 && vy0) ? fx * (1.f - fy) : 0.f;
            float w2 = (vx0 && vy1) ? (1.f - fx) * fy : 0.f;
            float w3 = (vx1 && vy1) ? fx * fy : 0.f;
            offs[p * 4 + vi * 2 + 0] = p00 | (p01 << 16);
            offs[p * 4 + vi * 2 + 1] = p10 | (p11 << 16);
            __half2 ha = __floats2half2_rn(w0, w1);
            __half2 hb = __floats2half2_rn(w2, w3);
            wgts[p * 4 + vi * 2 + 0] = *(unsigned int*)&ha;
            wgts[p * 4 + vi * 2 + 1] = *(unsigned int*)&hb;
        }
    }
    __syncthreads();

    const ushort* b1 = featT + (size_t)(1 * Bb + b) * HW * Cc;
    const ushort* b2 = featT + (size_t)(2 * Bb + b) * HW * Cc;
    const ushort* br = featT + (size_t)b * HW * Cc;

    // ---- stage B: gather items (slot, c16 0..1): 648 items, f16 math ----
#pragma unroll 1
    for (int i = tid; i < 648; i += 256) {
        int p = i >> 1, half16 = i & 1;
        int c16 = half16 << 4;                 // channel offset 0 or 16
        int pyt = p / 18, pxt = p - pyt * 18;
        int gy = tileY * 16 + pyt - 1, gx = tileX * 16 + pxt - 1;
        int sw0 = ((half16 * 2 + 0) ^ (p & 3)) * 8;
        int sw1 = ((half16 * 2 + 1) ^ (p & 3)) * 8;
        ushort* dst0 = &vsh[p * VS + sw0];
        ushort* dst1 = &vsh[p * VS + sw1];
        if ((unsigned)gy >= (unsigned)Hh || (unsigned)gx >= (unsigned)Ww) {
            *(uint4*)dst0 = make_uint4(0u, 0u, 0u, 0u);
            *(uint4*)dst1 = make_uint4(0u, 0u, 0u, 0u);
            continue;
        }
        uint4 oo = *(const uint4*)&offs[p * 4];
        uint4 wwp = *(const uint4*)&wgts[p * 4];
        int o00 = (int)(oo.x & 0xffffu) * Cc + c16;
        int o01 = (int)(oo.x >> 16)     * Cc + c16;
        int o10 = (int)(oo.y & 0xffffu) * Cc + c16;
        int o11 = (int)(oo.y >> 16)     * Cc + c16;
        int o20 = (int)(oo.z & 0xffffu) * Cc + c16;
        int o21 = (int)(oo.z >> 16)     * Cc + c16;
        int o30 = (int)(oo.w & 0xffffu) * Cc + c16;
        int o31 = (int)(oo.w >> 16)     * Cc + c16;
        int orf = (gy * Ww + gx) * Cc + c16;
        __half2 hv0 = *(__half2*)&wwp.x;   // v0: (w0,w1)
        __half2 hv1 = *(__half2*)&wwp.y;   // v0: (w2,w3)
        __half2 hv2 = *(__half2*)&wwp.z;   // v1: (w0,w1)
        __half2 hv3 = *(__half2*)&wwp.w;   // v1: (w2,w3)
        __half2 w00 = __half2half2(__low2half(hv0)), w01 = __half2half2(__high2half(hv0));
        __half2 w02 = __half2half2(__low2half(hv1)), w03 = __half2half2(__high2half(hv1));
        __half2 w10 = __half2half2(__low2half(hv2)), w11 = __half2half2(__high2half(hv2));
        __half2 w12 = __half2half2(__low2half(hv3)), w13 = __half2half2(__high2half(hv3));
        const __half2 third2 = __float2half2_rn(1.0f / 3.0f);
        union U { uint4 u; __half2 h[4]; };
#pragma unroll
        for (int h = 0; h < 2; ++h) {
            int e = h * 8;
            U R, C0, C1, C2, C3, E0, E1, E2, E3, V;
            R.u  = *(const uint4*)(br + orf + e);
            C0.u = *(const uint4*)(b1 + o00 + e);
            C1.u = *(const uint4*)(b1 + o01 + e);
            C2.u = *(const uint4*)(b1 + o10 + e);
            C3.u = *(const uint4*)(b1 + o11 + e);
            E0.u = *(const uint4*)(b2 + o20 + e);
            E1.u = *(const uint4*)(b2 + o21 + e);
            E2.u = *(const uint4*)(b2 + o30 + e);
            E3.u = *(const uint4*)(b2 + o31 + e);
#pragma unroll
            for (int k = 0; k < 4; ++k) {
                __half2 s1 = __hmul2(w00, C0.h[k]);
                s1 = __hfma2(w01, C1.h[k], s1);
                s1 = __hfma2(w02, C2.h[k], s1);
                s1 = __hfma2(w03, C3.h[k], s1);
                __half2 s2 = __hmul2(w10, E0.h[k]);
                s2 = __hfma2(w11, E1.h[k], s2);
                s2 = __hfma2(w12, E2.h[k], s2);
                s2 = __hfma2(w13, E3.h[k], s2);
                __half2 r = R.h[k];
                __half2 sum = __hadd2(__hadd2(r, s1), s2);
                __half2 sq = __hmul2(r, r);
                sq = __hfma2(s1, s1, sq);
                sq = __hfma2(s2, s2, sq);
                __half2 m = __hmul2(sum, third2);
                __half2 var = __hfma2(__hneg2(m), m, __hmul2(sq, third2));
                V.h[k] = var;
            }
            *(uint4*)(h ? dst1 : dst0) = V.u;
        }
    }
    __syncthreads();

    // ---- phase 2: f16 MFMA conv. Wave covers 4 row-groups of 16 pixels. ----
    const int lane = tid & 63;
    const int wave = tid >> 6;
    const int q = lane >> 4;      // k-chunk selector (channels q*8..+7) / D row quad
    const int n = lane & 15;      // A: pixel-x ; B/D: kd column
    uint4 bf[9];
#pragma unroll
    for (int tap = 0; tap < 9; ++tap)
        bf[tap] = *(const uint4*)(Bfr + ((tap * 64 + lane) << 3));
#pragma unroll 1
    for (int rr = 0; rr < 4; ++rr) {
        int row = wave * 4 + rr;            // ty of this 16-pixel row-group
        f32x4 acc = {0.f, 0.f, 0.f, 0.f};
#pragma unroll
        for (int tap = 0; tap < 9; ++tap) {
            int kh = tap / 3, kw = tap - 3 * (tap / 3);
            int slot = (row + kh) * 18 + n + kw;
            union { uint4 u; f16x8 v; } A, Bf;
            A.u  = *(const uint4*)&vsh[slot * VS + (q ^ (slot & 3)) * 8];
            Bf.u = bf[tap];
            acc = __builtin_amdgcn_mfma_f32_16x16x32_f16(A.v, Bf.v, acc, 0, 0, 0);
        }
        if (n < 3) {   // lane holds D[pixel-x = q*4+reg][kd = n]; store 4 px as f16
            int gy = tileY * 16 + row;
            int gxb = tileX * 16 + q * 4;
            union { uint2 u; ushort s[4]; } pk;
#pragma unroll
            for (int j = 0; j < 4; ++j) {
                __half h = __float2half(acc[j]);
                pk.s[j] = *(ushort*)&h;
            }
            *(uint2*)&S[((size_t)(b * 3 + n) * Dd + d) * HW + (size_t)gy * Ww + gxb] = pk.u;
        }
    }
}

// ---------------- K3: cost, softmax, depth + conf; 2 px/thread, 4-way d ----
// R12: each thread carries 2 adjacent pixels (uint = 2 f16 per load), so a
// 16-lane group covers 32 contiguous pixels -> 64 B-coalesced segments per
// (n,d); wave-load count halves vs R11. Reductions per component via
// __shfl_xor(16/32) as before.
__global__ __launch_bounds__(256)
void k_post(const ushort* __restrict__ S, const float* __restrict__ dvals,
            float* __restrict__ out) {
    const int tid = threadIdx.x;
    const int lane = tid & 63, wave = tid >> 6;
    const int q = lane >> 4;                        // d-chunk: d = q*12 + j
    const int pl = lane & 15;                       // pixel-pair within group
    int gid = ((blockIdx.x * 4 + wave) * 16 + pl) * 2;   // global pixel (even)
    int b = gid / HW;
    int pix = gid - b * HW;
    const ushort* S0 = S + ((size_t)(b * 3 + 0) * Dd) * HW + pix;
    const ushort* S1 = S + ((size_t)(b * 3 + 1) * Dd) * HW + pix;
    const ushort* S2 = S + ((size_t)(b * 3 + 2) * Dd) * HW + pix;
    const int d0 = q * 12;
    float2 cost[12];
#pragma unroll
    for (int j = 0; j < 12; ++j) {
        int dd = d0 + j;
        float2 c = __half22float2(*(const __half2*)&S1[(size_t)dd * HW]);
        if (dd > 0) {
            float2 a = __half22float2(*(const __half2*)&S0[(size_t)(dd - 1) * HW]);
            c.x += a.x; c.y += a.y;
        }
        if (dd < Dd - 1) {
            float2 a = __half22float2(*(const __half2*)&S2[(size_t)(dd + 1) * HW]);
            c.x += a.x; c.y += a.y;
        }
        cost[j] = c;
    }
    float mx = cost[0].x, my = cost[0].y;
#pragma unroll
    for (int j = 1; j < 12; ++j) { mx = fmaxf(mx, cost[j].x); my = fmaxf(my, cost[j].y); }
    mx = fmaxf(mx, __shfl_xor(mx, 16)); mx = fmaxf(mx, __shfl_xor(mx, 32));
    my = fmaxf(my, __shfl_xor(my, 16)); my = fmaxf(my, __shfl_xor(my, 32));
    float sx = 0.f, sy = 0.f, depx = 0.f, depy = 0.f, dix = 0.f, diy = 0.f;
#pragma unroll
    for (int j = 0; j < 12; ++j) {
        float dv = dvals[b * Dd + d0 + j];
        float fd = (float)(d0 + j);
        float ex = __expf(cost[j].x - mx);
        float ey = __expf(cost[j].y - my);
        cost[j].x = ex; cost[j].y = ey;
        sx += ex; sy += ey;
        depx += ex * dv; depy += ey * dv;
        dix += ex * fd;  diy += ey * fd;
    }
    sx += __shfl_xor(sx, 16); sx += __shfl_xor(sx, 32);
    sy += __shfl_xor(sy, 16); sy += __shfl_xor(sy, 32);
    depx += __shfl_xor(depx, 16); depx += __shfl_xor(depx, 32);
    depy += __shfl_xor(depy, 16); depy += __shfl_xor(depy, 32);
    dix += __shfl_xor(dix, 16); dix += __shfl_xor(dix, 32);
    diy += __shfl_xor(diy, 16); diy += __shfl_xor(diy, 32);
    float invx = 1.0f / sx, invy = 1.0f / sy;
    int didx = min(max((int)(dix * invx), 0), Dd - 1);
    int didy = min(max((int)(diy * invy), 0), Dd - 1);
    float wx = 0.f, wy = 0.f;
#pragma unroll
    for (int j = 0; j < 12; ++j) {
        int dd = d0 + j;
        wx += ((dd >= didx - 1) && (dd <= didx + 2)) ? cost[j].x : 0.f;
        wy += ((dd >= didy - 1) && (dd <= didy + 2)) ? cost[j].y : 0.f;
    }
    wx += __shfl_xor(wx, 16); wx += __shfl_xor(wx, 32);
    wy += __shfl_xor(wy, 16); wy += __shfl_xor(wy, 32);
    if (q == 0) {
        *(float2*)&out[gid] = make_float2(depx * invx, depy * invy);
        *(float2*)&out[Bb * HW + gid] = make_float2(wx * invx, wy * invy);
    }
}

// ---------------- launch ----------------------------------------------------
extern "C" void kernel_launch(void* const* d_in, const int* in_sizes, int n_in,
                              void* d_out, int out_size, void* d_ws, size_t ws_size,
                              hipStream_t stream) {
    const float* features = (const float*)d_in[0];   // (V,B,C,H,W)
    const float* pm       = (const float*)d_in[1];   // (B,V,4,4)
    const float* dvals    = (const float*)d_in[2];   // (B,D)
    const float* reg_w    = (const float*)d_in[4];   // (1,C,3,3,3)
    float* outp = (float*)d_out;

    char* ws = (char*)d_ws;
    ushort* featT = (ushort*)ws;                                 // V*B*H*W*C f16
    size_t featT_bytes = (size_t)Vv * Bb * Hh * Ww * Cc * sizeof(ushort);
    float* P = (float*)(ws + featT_bytes);                       // 48 floats
    ushort* S = (ushort*)(ws + featT_bytes + 512);               // B*3*D*H*W f16
    size_t S_bytes = (size_t)Bb * 3 * Dd * HW * sizeof(ushort);
    ushort* Bfr = (ushort*)(ws + featT_bytes + 512 + S_bytes);   // 9*64*8 f16

    k_transpose<<<Vv * Bb * Hh, 256, 0, stream>>>(features, pm, reg_w, featT, P, Bfr);
    k_main<<<dim3(80, Dd, Bb), 256, 0, stream>>>(featT, P, dvals, Bfr, S);
    k_post<<<(Bb * HW) / 128, 256, 0, stream>>>(S, dvals, outp);
}